// Round 15
// baseline (289.683 us; speedup 1.0000x reference)
//
#include <hip/hip_runtime.h>
#include <hip/hip_fp16.h>
#include <cstdint>
#include <cstddef>

typedef _Float16 f16x8 __attribute__((ext_vector_type(8)));
typedef float f32x4 __attribute__((ext_vector_type(4)));

__device__ __forceinline__ float exp_am8(float a) {
    // exp(a-8) == 2^(a*log2e - 8*log2e); single v_exp_f32
    return __builtin_amdgcn_exp2f(fmaf(a, 1.442695040888963f, -11.541560327111707f));
}

// ================= CSR build: bucket-first, no per-dst global histogram =================
__global__ __launch_bounds__(256) void bucket_hist(const int* __restrict__ dA,
                                                   int* __restrict__ bcntA, int shA,
                                                   const int* __restrict__ dB,
                                                   int* __restrict__ bcntB, int shB,
                                                   int E, int nblkA) {
    __shared__ int h[256];
    const int* dst; int* bcnt; int sh; int base;
    if ((int)blockIdx.x < nblkA) { dst = dA; bcnt = bcntA; sh = shA; base = blockIdx.x * 4096; }
    else { dst = dB; bcnt = bcntB; sh = shB; base = (blockIdx.x - nblkA) * 4096; }
    int t = threadIdx.x;
    h[t] = 0;
    __syncthreads();
#pragma unroll
    for (int j = 0; j < 16; ++j) {
        int i = base + j * 256 + t;
        if (i < E) atomicAdd(&h[dst[i] >> sh], 1);
    }
    __syncthreads();
    int c = h[t];
    if (c > 0) atomicAdd(&bcnt[t], c);
}

__global__ void bucket_scan(const int* __restrict__ bcntA, int nbkA,
                            int* __restrict__ bbaseA, int* __restrict__ bcurA,
                            int* __restrict__ offA, int nA,
                            const int* __restrict__ bcntB, int nbkB,
                            int* __restrict__ bbaseB, int* __restrict__ bcurB,
                            int* __restrict__ offB, int nB, int E) {
    int t = threadIdx.x;
    if (t == 0) {
        int run = 0;
        for (int i = 0; i < nbkA; ++i) { bbaseA[i] = run; bcurA[i] = run; run += bcntA[i]; }
        bbaseA[nbkA] = run;
        offA[nA] = E;
    }
    if (t == 64) {
        int run = 0;
        for (int i = 0; i < nbkB; ++i) { bbaseB[i] = run; bcurB[i] = run; run += bcntB[i]; }
        bbaseB[nbkB] = run;
        offB[nB] = E;
    }
}

__global__ __launch_bounds__(256) void bucket_scatter(
    const int* __restrict__ srcA, const int* __restrict__ dstA,
    int* __restrict__ bcurA, unsigned* __restrict__ pairsA,
    const int* __restrict__ srcB, const int* __restrict__ dstB,
    int* __restrict__ bcurB, unsigned* __restrict__ pairsB,
    int E, int nblkA, int shA, int shB, int srcbits) {
    __shared__ int bcnt[256];
    __shared__ int bbase[256];
    const int* src; const int* dst; int* bcur; unsigned* pairs; int sh; int base;
    if ((int)blockIdx.x < nblkA) {
        src = srcA; dst = dstA; bcur = bcurA; pairs = pairsA; sh = shA;
        base = blockIdx.x * 4096;
    } else {
        src = srcB; dst = dstB; bcur = bcurB; pairs = pairsB; sh = shB;
        base = (blockIdx.x - nblkA) * 4096;
    }
    int t = threadIdx.x;
    int msk = (1 << sh) - 1;
    bcnt[t] = 0;
    __syncthreads();
    int sreg[16], dreg[16];
#pragma unroll
    for (int j = 0; j < 16; ++j) {
        int i = base + j * 256 + t;
        if (i < E) {
            sreg[j] = src[i];
            dreg[j] = dst[i];
            atomicAdd(&bcnt[dreg[j] >> sh], 1);
        } else {
            dreg[j] = -1;
        }
    }
    __syncthreads();
    {
        int c = bcnt[t];
        int g = (c > 0) ? atomicAdd(&bcur[t], c) : 0;
        bbase[t] = g;
        bcnt[t] = 0;
    }
    __syncthreads();
#pragma unroll
    for (int j = 0; j < 16; ++j) {
        if (dreg[j] >= 0) {
            int b = dreg[j] >> sh;
            int r = atomicAdd(&bcnt[b], 1);
            pairs[bbase[b] + r] = ((unsigned)(dreg[j] & msk) << srcbits) | (unsigned)sreg[j];
        }
    }
}

__global__ __launch_bounds__(256) void bucket_expand2(
    const unsigned* __restrict__ pairsA, const int* __restrict__ bbaseA, int nA,
    int* __restrict__ offA, int* __restrict__ csrA, int shA, int nbA,
    const unsigned* __restrict__ pairsB, const int* __restrict__ bbaseB, int nB,
    int* __restrict__ offB, int* __restrict__ csrB, int shB, int srcbits) {
    __shared__ int lcnt[1024];
    __shared__ int red[256];
    const unsigned* pairs; const int* bbase; int n; int* off; int* csr; int sh; int b;
    if ((int)blockIdx.x < nbA) {
        pairs = pairsA; bbase = bbaseA; n = nA; off = offA; csr = csrA; sh = shA;
        b = blockIdx.x;
    } else {
        pairs = pairsB; bbase = bbaseB; n = nB; off = offB; csr = csrB; sh = shB;
        b = blockIdx.x - nbA;
    }
    int dpb = 1 << sh;
    int d0 = b << sh;
    int t = threadIdx.x;
    unsigned smask = (1u << srcbits) - 1u;
    for (int dl = t; dl < dpb; dl += 256) lcnt[dl] = 0;
    __syncthreads();
    int pbeg = bbase[b], pend = bbase[b + 1];
    for (int i = pbeg + t; i < pend; i += 256)
        atomicAdd(&lcnt[pairs[i] >> srcbits], 1);
    __syncthreads();
    int per = (dpb + 255) >> 8;
    int i0 = t * per;
    int s = 0;
    for (int j = 0; j < per; ++j) {
        int dl = i0 + j;
        if (dl < dpb) s += lcnt[dl];
    }
    red[t] = s;
    __syncthreads();
    for (int st = 1; st < 256; st <<= 1) {
        int tmp = (t >= st) ? red[t - st] : 0;
        __syncthreads();
        red[t] += tmp;
        __syncthreads();
    }
    int run = pbeg + red[t] - s;
    for (int j = 0; j < per; ++j) {
        int dl = i0 + j;
        if (dl < dpb) {
            int c = lcnt[dl];
            if (d0 + dl < n) off[d0 + dl] = run;
            lcnt[dl] = run;
            run += c;
        }
    }
    __syncthreads();
    for (int i = pbeg + t; i < pend; i += 256) {
        unsigned p = pairs[i];
        int dl = (int)(p >> srcbits);
        int pos = atomicAdd(&lcnt[dl], 1);
        csr[pos] = (int)(p & smask);
    }
}

// ========== fragment-ordered W pack — all 4 matrices in ONE launch ==========
// Wp[((ct*NKB+kb)*64 + (lr+16*lk))*8 + e] = W^T[ct*16+lr][kb*32+lk*8+e]
__global__ __launch_bounds__(256) void pack_w_all(
    const float* __restrict__ Wa0, const float* __restrict__ Wb0, _Float16* __restrict__ P0,
    const float* __restrict__ Wa1, const float* __restrict__ Wb1, _Float16* __restrict__ P1,
    const float* __restrict__ Wa2, const float* __restrict__ Wb2, _Float16* __restrict__ P2,
    const float* __restrict__ Wa3, const float* __restrict__ Wb3, _Float16* __restrict__ P3) {
    int b = blockIdx.x;
    const float* Wa; const float* Wb; _Float16* Wp; int K; int lb;
    if (b < 64)       { Wa = Wa0; Wb = Wb0; Wp = P0; K = 128; lb = b; }
    else if (b < 128) { Wa = Wa1; Wb = Wb1; Wp = P1; K = 128; lb = b - 64; }
    else if (b < 160) { Wa = Wa2; Wb = Wb2; Wp = P2; K = 64;  lb = b - 128; }
    else              { Wa = Wa3; Wb = Wb3; Wp = P3; K = 64;  lb = b - 160; }
    int NKB = K / 32;
    int i = lb * 256 + threadIdx.x;
    if (i >= 128 * K) return;
    int k = i >> 7, c = i & 127;
    float v = (c < 64) ? Wa[k * 64 + c] : Wb[k * 64 + (c - 64)];
    int ct = c >> 4, lr = c & 15, kb = k >> 5, lk = (k & 31) >> 3, e = k & 7;
    Wp[((ct * NKB + kb) * 64 + (lr + 16 * lk)) * 8 + e] = (_Float16)v;
}

// ================= MFMA dual projection v3: zero-conflict LDS, X direct-to-reg ========
template <int K, typename TIN>
__global__ __launch_bounds__(256) void proj_mfma3_kernel(const TIN* __restrict__ X, int N,
                                                         const _Float16* __restrict__ Wp,
                                                         const float* __restrict__ a0v,
                                                         const float* __restrict__ a1v,
                                                         __half* __restrict__ out0,
                                                         float* __restrict__ al0,
                                                         float* __restrict__ al1) {
    constexpr int NKB = K / 32;
    __shared__ __align__(16) _Float16 Wlds[128 * K];
    int t = threadIdx.x;
    constexpr int NV = (128 * K) / 8;
#pragma unroll
    for (int i = t; i < NV; i += 256)
        ((uint4*)Wlds)[i] = ((const uint4*)Wp)[i];
    __syncthreads();

    int rt = blockIdx.x * 64;
    int wv = t >> 6, lane = t & 63, lr = lane & 15, lk = lane >> 4;
    int row = rt + wv * 16 + lr;
    int rowc = row < N ? row : N - 1;

    f32x4 acc[8];
#pragma unroll
    for (int i = 0; i < 8; ++i) acc[i] = f32x4{0.f, 0.f, 0.f, 0.f};

    const f16x8* Wf = (const f16x8*)Wlds;
#pragma unroll
    for (int kb = 0; kb < NKB; ++kb) {
        f16x8 bf;
        if constexpr (sizeof(TIN) == 4) {
            const float* xr = (const float*)X + (size_t)rowc * K + kb * 32 + lk * 8;
            float4 x0 = *(const float4*)xr;
            float4 x1 = *(const float4*)(xr + 4);
            bf[0] = (_Float16)x0.x; bf[1] = (_Float16)x0.y;
            bf[2] = (_Float16)x0.z; bf[3] = (_Float16)x0.w;
            bf[4] = (_Float16)x1.x; bf[5] = (_Float16)x1.y;
            bf[6] = (_Float16)x1.z; bf[7] = (_Float16)x1.w;
        } else {
            bf = *(const f16x8*)((const _Float16*)X + (size_t)rowc * K + kb * 32 + lk * 8);
        }
#pragma unroll
        for (int ct = 0; ct < 8; ++ct) {
            acc[ct] = __builtin_amdgcn_mfma_f32_16x16x32_f16(Wf[(ct * NKB + kb) * 64 + lane],
                                                             bf, acc[ct], 0, 0, 0);
        }
    }

    float p0 = 0.f, p1 = 0.f;
#pragma unroll
    for (int ct = 0; ct < 4; ++ct) {
        float4 aq = ((const float4*)a0v)[ct * 4 + lk];
        f32x4 v = acc[ct];
        p0 += v[0] * aq.x + v[1] * aq.y + v[2] * aq.z + v[3] * aq.w;
    }
#pragma unroll
    for (int ct = 0; ct < 4; ++ct) {
        float4 aq = ((const float4*)a1v)[ct * 4 + lk];
        f32x4 v = acc[4 + ct];
        p1 += v[0] * aq.x + v[1] * aq.y + v[2] * aq.z + v[3] * aq.w;
    }
    p0 += __shfl_xor(p0, 16); p0 += __shfl_xor(p0, 32);
    p1 += __shfl_xor(p1, 16); p1 += __shfl_xor(p1, 32);
    if (row < N) {
#pragma unroll
        for (int ct = 0; ct < 4; ++ct) {
            f32x4 v = acc[ct];
            __half2 h01 = __floats2half2_rn(v[0], v[1]);
            __half2 h23 = __floats2half2_rn(v[2], v[3]);
            uint2 pk;
            pk.x = *(const unsigned int*)&h01;
            pk.y = *(const unsigned int*)&h23;
            *(uint2*)(out0 + ((size_t)row << 6) + ct * 16 + lk * 4) = pk;
        }
        if (lane < 16) { al0[row] = p0; al1[row] = p1; }
    }
}

// ========== GAT aggregation v7: 16-lane group/dst, padded LDS, 16-deep gathers ======
// exp(alpha-8) == softmax-identical (no max pass). Pass 1 (16-lane stripe): w + f32 denom,
// {half2(w,w),src} cached in LDS (row pad +2 -> 2-way bank alias only). Pass 2: uint4 LDS
// reads (2 edges) + 8B row-slice gathers, 16-deep unroll = 64 outstanding loads/wave.
#define AGG_CAP 128
#define AGG_PAD 130

template <int RELU, int HALF_OUT>
__global__ __launch_bounds__(256) void gat_aggregate7(
    const int* __restrict__ off0, const int* __restrict__ csr0,
    const __half* __restrict__ hs0, const float* __restrict__ als0,
    const float* __restrict__ ald0, const float* __restrict__ bias0,
    void* __restrict__ outp0, int n0,
    const int* __restrict__ off1, const int* __restrict__ csr1,
    const __half* __restrict__ hs1, const float* __restrict__ als1,
    const float* __restrict__ ald1, const float* __restrict__ bias1,
    void* __restrict__ outp1, int n1,
    int nb0) {
    __shared__ uint2 wP[16][AGG_PAD];
    int t = threadIdx.x;
    int slot = t >> 4;
    int sub = t & 15;

    const int* off; const int* csr; const __half* hs; const float* als;
    const float* ald; const float* bias; void* outp; int nd; int b;
    if (blockIdx.x < (unsigned)nb0) {
        b = blockIdx.x;
        off = off0; csr = csr0; hs = hs0; als = als0; ald = ald0; bias = bias0;
        outp = outp0; nd = n0;
    } else {
        b = blockIdx.x - nb0;
        off = off1; csr = csr1; hs = hs1; als = als1; ald = ald1; bias = bias1;
        outp = outp1; nd = n1;
    }
    int d = b * 16 + slot;
    bool active = d < nd;
    int beg = 0, deg = 0;
    float aldv = 0.f;
    if (active) {
        beg = off[d];
        deg = off[d + 1] - beg;
        aldv = ald[d];
    }
    float4 bl4 = ((const float4*)bias)[sub];
    uint2* WP = wP[slot];

    // pass 1: weights + denom (16-lane stripe)
    float sum = 0.f;
    for (int i = sub; i < deg; i += 16) {
        int s = csr[beg + i];
        float a = als[s] + aldv;
        a = (a >= 0.f) ? a : 0.2f * a;
        float w = exp_am8(a);
        sum += w;
        if (i < AGG_CAP) {
            __half hw = __float2half_rn(w);
            __half2 h2 = __half2half2(hw);
            WP[i] = make_uint2(*(const unsigned int*)&h2, (unsigned int)s);
        }
    }
    sum += __shfl_xor(sum, 1);
    sum += __shfl_xor(sum, 2);
    sum += __shfl_xor(sum, 4);
    sum += __shfl_xor(sum, 8);
    float inv = 1.f / fmaxf(sum, 1e-16f);

    // pass 2: 4 channels/lane; 16-deep then 8-deep then 2-step remainder
    int dc = deg < AGG_CAP ? deg : AGG_CAP;
    const uint2* hs4 = (const uint2*)hs;   // row = 16 x uint2 (64 ch)
    __half2 z = __floats2half2_rn(0.f, 0.f);
    __half2 aA = z, aB = z, aC = z, aD = z;
    int i = 0;
    for (; i + 16 <= dc; i += 16) {
        uint4 q0 = *(const uint4*)&WP[i];
        uint4 q1 = *(const uint4*)&WP[i + 2];
        uint4 q2 = *(const uint4*)&WP[i + 4];
        uint4 q3 = *(const uint4*)&WP[i + 6];
        uint4 q4 = *(const uint4*)&WP[i + 8];
        uint4 q5 = *(const uint4*)&WP[i + 10];
        uint4 q6 = *(const uint4*)&WP[i + 12];
        uint4 q7 = *(const uint4*)&WP[i + 14];
        uint2 v0 = hs4[(size_t)q0.y * 16 + sub];
        uint2 v1 = hs4[(size_t)q0.w * 16 + sub];
        uint2 v2 = hs4[(size_t)q1.y * 16 + sub];
        uint2 v3 = hs4[(size_t)q1.w * 16 + sub];
        uint2 v4 = hs4[(size_t)q2.y * 16 + sub];
        uint2 v5 = hs4[(size_t)q2.w * 16 + sub];
        uint2 v6 = hs4[(size_t)q3.y * 16 + sub];
        uint2 v7 = hs4[(size_t)q3.w * 16 + sub];
        uint2 v8 = hs4[(size_t)q4.y * 16 + sub];
        uint2 v9 = hs4[(size_t)q4.w * 16 + sub];
        uint2 vA = hs4[(size_t)q5.y * 16 + sub];
        uint2 vB = hs4[(size_t)q5.w * 16 + sub];
        uint2 vC = hs4[(size_t)q6.y * 16 + sub];
        uint2 vD = hs4[(size_t)q6.w * 16 + sub];
        uint2 vE = hs4[(size_t)q7.y * 16 + sub];
        uint2 vF = hs4[(size_t)q7.w * 16 + sub];
        aA = __hfma2(*(const __half2*)&q0.x, *(const __half2*)&v0.x, aA);
        aB = __hfma2(*(const __half2*)&q0.x, *(const __half2*)&v0.y, aB);
        aC = __hfma2(*(const __half2*)&q0.z, *(const __half2*)&v1.x, aC);
        aD = __hfma2(*(const __half2*)&q0.z, *(const __half2*)&v1.y, aD);
        aA = __hfma2(*(const __half2*)&q1.x, *(const __half2*)&v2.x, aA);
        aB = __hfma2(*(const __half2*)&q1.x, *(const __half2*)&v2.y, aB);
        aC = __hfma2(*(const __half2*)&q1.z, *(const __half2*)&v3.x, aC);
        aD = __hfma2(*(const __half2*)&q1.z, *(const __half2*)&v3.y, aD);
        aA = __hfma2(*(const __half2*)&q2.x, *(const __half2*)&v4.x, aA);
        aB = __hfma2(*(const __half2*)&q2.x, *(const __half2*)&v4.y, aB);
        aC = __hfma2(*(const __half2*)&q2.z, *(const __half2*)&v5.x, aC);
        aD = __hfma2(*(const __half2*)&q2.z, *(const __half2*)&v5.y, aD);
        aA = __hfma2(*(const __half2*)&q3.x, *(const __half2*)&v6.x, aA);
        aB = __hfma2(*(const __half2*)&q3.x, *(const __half2*)&v6.y, aB);
        aC = __hfma2(*(const __half2*)&q3.z, *(const __half2*)&v7.x, aC);
        aD = __hfma2(*(const __half2*)&q3.z, *(const __half2*)&v7.y, aD);
        aA = __hfma2(*(const __half2*)&q4.x, *(const __half2*)&v8.x, aA);
        aB = __hfma2(*(const __half2*)&q4.x, *(const __half2*)&v8.y, aB);
        aC = __hfma2(*(const __half2*)&q4.z, *(const __half2*)&v9.x, aC);
        aD = __hfma2(*(const __half2*)&q4.z, *(const __half2*)&v9.y, aD);
        aA = __hfma2(*(const __half2*)&q5.x, *(const __half2*)&vA.x, aA);
        aB = __hfma2(*(const __half2*)&q5.x, *(const __half2*)&vA.y, aB);
        aC = __hfma2(*(const __half2*)&q5.z, *(const __half2*)&vB.x, aC);
        aD = __hfma2(*(const __half2*)&q5.z, *(const __half2*)&vB.y, aD);
        aA = __hfma2(*(const __half2*)&q6.x, *(const __half2*)&vC.x, aA);
        aB = __hfma2(*(const __half2*)&q6.x, *(const __half2*)&vC.y, aB);
        aC = __hfma2(*(const __half2*)&q6.z, *(const __half2*)&vD.x, aC);
        aD = __hfma2(*(const __half2*)&q6.z, *(const __half2*)&vD.y, aD);
        aA = __hfma2(*(const __half2*)&q7.x, *(const __half2*)&vE.x, aA);
        aB = __hfma2(*(const __half2*)&q7.x, *(const __half2*)&vE.y, aB);
        aC = __hfma2(*(const __half2*)&q7.z, *(const __half2*)&vF.x, aC);
        aD = __hfma2(*(const __half2*)&q7.z, *(const __half2*)&vF.y, aD);
    }
    for (; i + 8 <= dc; i += 8) {
        uint4 q0 = *(const uint4*)&WP[i];
        uint4 q1 = *(const uint4*)&WP[i + 2];
        uint4 q2 = *(const uint4*)&WP[i + 4];
        uint4 q3 = *(const uint4*)&WP[i + 6];
        uint2 v0 = hs4[(size_t)q0.y * 16 + sub];
        uint2 v1 = hs4[(size_t)q0.w * 16 + sub];
        uint2 v2 = hs4[(size_t)q1.y * 16 + sub];
        uint2 v3 = hs4[(size_t)q1.w * 16 + sub];
        uint2 v4 = hs4[(size_t)q2.y * 16 + sub];
        uint2 v5 = hs4[(size_t)q2.w * 16 + sub];
        uint2 v6 = hs4[(size_t)q3.y * 16 + sub];
        uint2 v7 = hs4[(size_t)q3.w * 16 + sub];
        aA = __hfma2(*(const __half2*)&q0.x, *(const __half2*)&v0.x, aA);
        aB = __hfma2(*(const __half2*)&q0.x, *(const __half2*)&v0.y, aB);
        aC = __hfma2(*(const __half2*)&q0.z, *(const __half2*)&v1.x, aC);
        aD = __hfma2(*(const __half2*)&q0.z, *(const __half2*)&v1.y, aD);
        aA = __hfma2(*(const __half2*)&q1.x, *(const __half2*)&v2.x, aA);
        aB = __hfma2(*(const __half2*)&q1.x, *(const __half2*)&v2.y, aB);
        aC = __hfma2(*(const __half2*)&q1.z, *(const __half2*)&v3.x, aC);
        aD = __hfma2(*(const __half2*)&q1.z, *(const __half2*)&v3.y, aD);
        aA = __hfma2(*(const __half2*)&q2.x, *(const __half2*)&v4.x, aA);
        aB = __hfma2(*(const __half2*)&q2.x, *(const __half2*)&v4.y, aB);
        aC = __hfma2(*(const __half2*)&q2.z, *(const __half2*)&v5.x, aC);
        aD = __hfma2(*(const __half2*)&q2.z, *(const __half2*)&v5.y, aD);
        aA = __hfma2(*(const __half2*)&q3.x, *(const __half2*)&v6.x, aA);
        aB = __hfma2(*(const __half2*)&q3.x, *(const __half2*)&v6.y, aB);
        aC = __hfma2(*(const __half2*)&q3.z, *(const __half2*)&v7.x, aC);
        aD = __hfma2(*(const __half2*)&q3.z, *(const __half2*)&v7.y, aD);
    }
    for (; i + 2 <= dc; i += 2) {
        uint4 q = *(const uint4*)&WP[i];
        uint2 v0 = hs4[(size_t)q.y * 16 + sub];
        uint2 v1 = hs4[(size_t)q.w * 16 + sub];
        aA = __hfma2(*(const __half2*)&q.x, *(const __half2*)&v0.x, aA);
        aB = __hfma2(*(const __half2*)&q.x, *(const __half2*)&v0.y, aB);
        aC = __hfma2(*(const __half2*)&q.z, *(const __half2*)&v1.x, aC);
        aD = __hfma2(*(const __half2*)&q.z, *(const __half2*)&v1.y, aD);
    }
    if (i < dc) {
        uint2 u = WP[i];
        uint2 v = hs4[(size_t)u.y * 16 + sub];
        aA = __hfma2(*(const __half2*)&u.x, *(const __half2*)&v.x, aA);
        aB = __hfma2(*(const __half2*)&u.x, *(const __half2*)&v.y, aB);
    }
    // fallback for deg > AGG_CAP (recompute weight; statistically never at mean deg <= 20)
    for (int j = AGG_CAP; j < deg; ++j) {
        int s = csr[beg + j];
        float a = als[s] + aldv;
        a = (a >= 0.f) ? a : 0.2f * a;
        __half hw = __float2half_rn(exp_am8(a));
        __half2 w2 = __half2half2(hw);
        uint2 v = hs4[(size_t)s * 16 + sub];
        aA = __hfma2(w2, *(const __half2*)&v.x, aA);
        aB = __hfma2(w2, *(const __half2*)&v.y, aB);
    }
    float2 fA = __half22float2(aA);
    float2 fB = __half22float2(aB);
    float2 fC = __half22float2(aC);
    float2 fD = __half22float2(aD);
    float o0 = (fA.x + fC.x) * inv + bl4.x;
    float o1 = (fA.y + fC.y) * inv + bl4.y;
    float o2 = (fB.x + fD.x) * inv + bl4.z;
    float o3 = (fB.y + fD.y) * inv + bl4.w;
    if (deg == 0) { o0 = bl4.x; o1 = bl4.y; o2 = bl4.z; o3 = bl4.w; }
    if (RELU) {
        o0 = fmaxf(o0, 0.f); o1 = fmaxf(o1, 0.f);
        o2 = fmaxf(o2, 0.f); o3 = fmaxf(o3, 0.f);
    }
    if (active) {
        if (HALF_OUT) {
            __half2 h01 = __floats2half2_rn(o0, o1);
            __half2 h23 = __floats2half2_rn(o2, o3);
            uint2 pk;
            pk.x = *(const unsigned int*)&h01;
            pk.y = *(const unsigned int*)&h23;
            ((uint2*)outp)[(size_t)d * 16 + sub] = pk;
        } else {
            ((float4*)outp)[(size_t)d * 16 + sub] = make_float4(o0, o1, o2, o3);
        }
    }
}

// ---------------- decoder (inline Wc = Wd1@Wd2 prep per block) ----------------
__global__ __launch_bounds__(256) void decoder3_kernel(const int* __restrict__ row,
                                                       const int* __restrict__ col,
                                                       const __half* __restrict__ zm2,
                                                       const __half* __restrict__ zc2,
                                                       const float* __restrict__ Wd1,
                                                       const float* __restrict__ bd1,
                                                       const float* __restrict__ Wd2,
                                                       const float* __restrict__ bd2,
                                                       float* __restrict__ out, int EL) {
    __shared__ float WcL[256];
    __shared__ float bcL[2];
    int t = threadIdx.x;
    {
        int k = t >> 1, c = t & 1;
        float s = 0.f;
        for (int j = 0; j < 64; ++j) s += Wd1[k * 64 + j] * Wd2[j * 2 + c];
        WcL[k * 2 + c] = s;
        if (t < 2) {
            float bv = bd2[t];
            for (int j = 0; j < 64; ++j) bv += bd1[j] * Wd2[j * 2 + t];
            bcL[t] = bv;
        }
    }
    __syncthreads();
    int lane = t & 63;
    int sub = lane & 31;
    int hw = (blockIdx.x * 256 + t) >> 5;
    int nhw = (gridDim.x * 256) >> 5;
    float4 wA = ((const float4*)WcL)[sub];
    float4 wB = ((const float4*)WcL)[32 + sub];
    float b0 = bcL[0], b1 = bcL[1];
    const __half2* zmh = (const __half2*)zm2;
    const __half2* zch = (const __half2*)zc2;
    for (int e = hw; e < EL; e += nhw) {
        int r = row[e], c = col[e];
        float2 f = __half22float2(zmh[((size_t)r << 5) + sub]);
        float2 g = __half22float2(zch[((size_t)c << 5) + sub]);
        float p0 = f.x * wA.x + f.y * wA.z + g.x * wB.x + g.y * wB.z;
        float p1 = f.x * wA.y + f.y * wA.w + g.x * wB.y + g.y * wB.w;
        p0 += __shfl_xor(p0, 1);  p1 += __shfl_xor(p1, 1);
        p0 += __shfl_xor(p0, 2);  p1 += __shfl_xor(p1, 2);
        p0 += __shfl_xor(p0, 4);  p1 += __shfl_xor(p1, 4);
        p0 += __shfl_xor(p0, 8);  p1 += __shfl_xor(p1, 8);
        p0 += __shfl_xor(p0, 16); p1 += __shfl_xor(p1, 16);
        if (sub == 0) *(float2*)(out + 2 * (size_t)e) = make_float2(p0 + b0, p1 + b1);
    }
}

// ---------------- launch ----------------
extern "C" void kernel_launch(void* const* d_in, const int* in_sizes, int n_in,
                              void* d_out, int out_size, void* d_ws, size_t ws_size,
                              hipStream_t stream) {
    const int D = 128;
    const float* x_m    = (const float*)d_in[0];
    const float* x_c    = (const float*)d_in[1];
    const int*   src_mc = (const int*)d_in[2];
    const int*   dst_mc = (const int*)d_in[3];
    const int*   src_cm = (const int*)d_in[4];
    const int*   dst_cm = (const int*)d_in[5];
    const int*   rowi   = (const int*)d_in[6];
    const int*   coli   = (const int*)d_in[7];
    const float* W1s_mc = (const float*)d_in[8];
    const float* W1d_mc = (const float*)d_in[9];
    const float* a1s_mc = (const float*)d_in[10];
    const float* a1d_mc = (const float*)d_in[11];
    const float* b1_mc  = (const float*)d_in[12];
    const float* W1s_cm = (const float*)d_in[13];
    const float* W1d_cm = (const float*)d_in[14];
    const float* a1s_cm = (const float*)d_in[15];
    const float* a1d_cm = (const float*)d_in[16];
    const float* b1_cm  = (const float*)d_in[17];
    const float* W2s_mc = (const float*)d_in[18];
    const float* W2d_mc = (const float*)d_in[19];
    const float* a2s_mc = (const float*)d_in[20];
    const float* a2d_mc = (const float*)d_in[21];
    const float* b2_mc  = (const float*)d_in[22];
    const float* W2s_cm = (const float*)d_in[23];
    const float* W2d_cm = (const float*)d_in[24];
    const float* a2s_cm = (const float*)d_in[25];
    const float* a2d_cm = (const float*)d_in[26];
    const float* b2_cm  = (const float*)d_in[27];
    const float* Wd1    = (const float*)d_in[28];
    const float* bd1    = (const float*)d_in[29];
    const float* Wd2    = (const float*)d_in[30];
    const float* bd2    = (const float*)d_in[31];

    const int N_M = in_sizes[0] / D;
    const int N_C = in_sizes[1] / D;
    const int E   = in_sizes[2];
    const int EL  = in_sizes[6];
    float* out = (float*)d_out;

    uint8_t* base = (uint8_t*)d_ws;
    size_t off = 0;
    auto carve = [&](size_t bytes) -> void* {
        void* p = base + off;
        off += (bytes + 255) & ~(size_t)255;
        return p;
    };
    __half* hsA_h = (__half*)carve((size_t)N_M * 64 * 2);
    __half* hsB_h = (__half*)carve((size_t)N_C * 64 * 2);
    __half* zm1_h = (__half*)carve((size_t)N_M * 64 * 2);
    __half* zc1_h = (__half*)carve((size_t)N_C * 64 * 2);
    __half* zm2_h = (__half*)carve((size_t)N_M * 64 * 2);
    __half* zc2_h = (__half*)carve((size_t)N_C * 64 * 2);
    float* als_mc = (float*)carve((size_t)N_M * 4);
    float* ald_cm = (float*)carve((size_t)N_M * 4);
    float* als_cm = (float*)carve((size_t)N_C * 4);
    float* ald_mc = (float*)carve((size_t)N_C * 4);
    int* off_mc = (int*)carve((size_t)(N_C + 1) * 4);
    int* off_cm = (int*)carve((size_t)(N_M + 1) * 4);
    int* csr_mc = (int*)carve((size_t)E * 4);
    int* csr_cm = (int*)carve((size_t)E * 4);
    unsigned* pairs_mc = (unsigned*)carve((size_t)E * 4);
    unsigned* pairs_cm = (unsigned*)carve((size_t)E * 4);
    int* bcnt_base = (int*)carve(512 * 4);
    int* bcnt_mc = bcnt_base;
    int* bcnt_cm = bcnt_base + 256;
    int* bbase_mc = (int*)carve(257 * 4);
    int* bbase_cm = (int*)carve(257 * 4);
    int* bcur_mc = (int*)carve(256 * 4);
    int* bcur_cm = (int*)carve(256 * 4);
    _Float16* wp1A = (_Float16*)carve(128 * 128 * 2);
    _Float16* wp1B = (_Float16*)carve(128 * 128 * 2);
    _Float16* wp2A = (_Float16*)carve(128 * 64 * 2);
    _Float16* wp2B = (_Float16*)carve(128 * 64 * 2);

    int shA = 0; while (((N_C + (1 << shA) - 1) >> shA) > 256) shA++;
    int shB = 0; while (((N_M + (1 << shB) - 1) >> shB) > 256) shB++;
    int nbkA = (N_C + (1 << shA) - 1) >> shA;
    int nbkB = (N_M + (1 << shB) - 1) >> shB;
    int maxN = N_M > N_C ? N_M : N_C;
    int srcbits = 1; while ((1 << srcbits) < maxN) srcbits++;

    // ---- W fragment pre-pack (single launch) ----
    pack_w_all<<<192, 256, 0, stream>>>(W1s_mc, W1d_cm, wp1A,
                                        W1s_cm, W1d_mc, wp1B,
                                        W2s_mc, W2d_cm, wp2A,
                                        W2s_cm, W2d_mc, wp2B);

    // ---- CSR build (bucket-first) ----
    hipMemsetAsync(bcnt_base, 0, 512 * 4, stream);
    int nblk = (E + 4095) / 4096;
    bucket_hist<<<2 * nblk, 256, 0, stream>>>(dst_mc, bcnt_mc, shA,
                                              dst_cm, bcnt_cm, shB, E, nblk);
    bucket_scan<<<1, 128, 0, stream>>>(bcnt_mc, nbkA, bbase_mc, bcur_mc, off_mc, N_C,
                                       bcnt_cm, nbkB, bbase_cm, bcur_cm, off_cm, N_M, E);
    bucket_scatter<<<2 * nblk, 256, 0, stream>>>(
        src_mc, dst_mc, bcur_mc, pairs_mc,
        src_cm, dst_cm, bcur_cm, pairs_cm, E, nblk, shA, shB, srcbits);
    bucket_expand2<<<nbkA + nbkB, 256, 0, stream>>>(
        pairs_mc, bbase_mc, N_C, off_mc, csr_mc, shA, nbkA,
        pairs_cm, bbase_cm, N_M, off_cm, csr_cm, shB, srcbits);

    int nb_c = (N_C + 15) / 16;
    int nb_m = (N_M + 15) / 16;

    // ---- Layer 1 (f32 inputs -> fp16 MFMA) ----
    proj_mfma3_kernel<128, float><<<(N_M + 63) / 64, 256, 0, stream>>>(
        x_m, N_M, wp1A, a1s_mc, a1d_cm, hsA_h, als_mc, ald_cm);
    proj_mfma3_kernel<128, float><<<(N_C + 63) / 64, 256, 0, stream>>>(
        x_c, N_C, wp1B, a1s_cm, a1d_mc, hsB_h, als_cm, ald_mc);
    gat_aggregate7<1, 1><<<nb_c + nb_m, 256, 0, stream>>>(
        off_mc, csr_mc, hsA_h, als_mc, ald_mc, b1_mc, zc1_h, N_C,
        off_cm, csr_cm, hsB_h, als_cm, ald_cm, b1_cm, zm1_h, N_M, nb_c);

    // ---- Layer 2 (fp16 inputs) ----
    proj_mfma3_kernel<64, __half><<<(N_M + 63) / 64, 256, 0, stream>>>(
        zm1_h, N_M, wp2A, a2s_mc, a2d_cm, hsA_h, als_mc, ald_cm);
    proj_mfma3_kernel<64, __half><<<(N_C + 63) / 64, 256, 0, stream>>>(
        zc1_h, N_C, wp2B, a2s_cm, a2d_mc, hsB_h, als_cm, ald_mc);
    gat_aggregate7<0, 1><<<nb_c + nb_m, 256, 0, stream>>>(
        off_mc, csr_mc, hsA_h, als_mc, ald_mc, b2_mc, zc2_h, N_C,
        off_cm, csr_cm, hsB_h, als_cm, ald_cm, b2_cm, zm2_h, N_M, nb_c);

    // ---- Decoder ----
    decoder3_kernel<<<2048, 256, 0, stream>>>(rowi, coli, zm2_h, zc2_h,
                                              Wd1, bd1, Wd2, bd2, out, EL);
}

// Round 16
// 273.149 us; speedup vs baseline: 1.0605x; 1.0605x over previous
//
#include <hip/hip_runtime.h>
#include <hip/hip_fp16.h>
#include <cstdint>
#include <cstddef>

typedef _Float16 f16x8 __attribute__((ext_vector_type(8)));
typedef float f32x4 __attribute__((ext_vector_type(4)));

__device__ __forceinline__ float exp_am8(float a) {
    // exp(a-8) == 2^(a*log2e - 8*log2e); single v_exp_f32
    return __builtin_amdgcn_exp2f(fmaf(a, 1.442695040888963f, -11.541560327111707f));
}

// ================= CSR build: bucket-first, no per-dst global histogram =================
__global__ __launch_bounds__(256) void bucket_hist(const int* __restrict__ dA,
                                                   int* __restrict__ bcntA, int shA,
                                                   const int* __restrict__ dB,
                                                   int* __restrict__ bcntB, int shB,
                                                   int E, int nblkA) {
    __shared__ int h[256];
    const int* dst; int* bcnt; int sh; int base;
    if ((int)blockIdx.x < nblkA) { dst = dA; bcnt = bcntA; sh = shA; base = blockIdx.x * 4096; }
    else { dst = dB; bcnt = bcntB; sh = shB; base = (blockIdx.x - nblkA) * 4096; }
    int t = threadIdx.x;
    h[t] = 0;
    __syncthreads();
#pragma unroll
    for (int j = 0; j < 16; ++j) {
        int i = base + j * 256 + t;
        if (i < E) atomicAdd(&h[dst[i] >> sh], 1);
    }
    __syncthreads();
    int c = h[t];
    if (c > 0) atomicAdd(&bcnt[t], c);
}

__global__ void bucket_scan(const int* __restrict__ bcntA, int nbkA,
                            int* __restrict__ bbaseA, int* __restrict__ bcurA,
                            int* __restrict__ offA, int nA,
                            const int* __restrict__ bcntB, int nbkB,
                            int* __restrict__ bbaseB, int* __restrict__ bcurB,
                            int* __restrict__ offB, int nB, int E) {
    int t = threadIdx.x;
    if (t == 0) {
        int run = 0;
        for (int i = 0; i < nbkA; ++i) { bbaseA[i] = run; bcurA[i] = run; run += bcntA[i]; }
        bbaseA[nbkA] = run;
        offA[nA] = E;
    }
    if (t == 64) {
        int run = 0;
        for (int i = 0; i < nbkB; ++i) { bbaseB[i] = run; bcurB[i] = run; run += bcntB[i]; }
        bbaseB[nbkB] = run;
        offB[nB] = E;
    }
}

__global__ __launch_bounds__(256) void bucket_scatter(
    const int* __restrict__ srcA, const int* __restrict__ dstA,
    int* __restrict__ bcurA, unsigned* __restrict__ pairsA,
    const int* __restrict__ srcB, const int* __restrict__ dstB,
    int* __restrict__ bcurB, unsigned* __restrict__ pairsB,
    int E, int nblkA, int shA, int shB, int srcbits) {
    __shared__ int bcnt[256];
    __shared__ int bbase[256];
    const int* src; const int* dst; int* bcur; unsigned* pairs; int sh; int base;
    if ((int)blockIdx.x < nblkA) {
        src = srcA; dst = dstA; bcur = bcurA; pairs = pairsA; sh = shA;
        base = blockIdx.x * 4096;
    } else {
        src = srcB; dst = dstB; bcur = bcurB; pairs = pairsB; sh = shB;
        base = (blockIdx.x - nblkA) * 4096;
    }
    int t = threadIdx.x;
    int msk = (1 << sh) - 1;
    bcnt[t] = 0;
    __syncthreads();
    int sreg[16], dreg[16];
#pragma unroll
    for (int j = 0; j < 16; ++j) {
        int i = base + j * 256 + t;
        if (i < E) {
            sreg[j] = src[i];
            dreg[j] = dst[i];
            atomicAdd(&bcnt[dreg[j] >> sh], 1);
        } else {
            dreg[j] = -1;
        }
    }
    __syncthreads();
    {
        int c = bcnt[t];
        int g = (c > 0) ? atomicAdd(&bcur[t], c) : 0;
        bbase[t] = g;
        bcnt[t] = 0;
    }
    __syncthreads();
#pragma unroll
    for (int j = 0; j < 16; ++j) {
        if (dreg[j] >= 0) {
            int b = dreg[j] >> sh;
            int r = atomicAdd(&bcnt[b], 1);
            pairs[bbase[b] + r] = ((unsigned)(dreg[j] & msk) << srcbits) | (unsigned)sreg[j];
        }
    }
}

__global__ __launch_bounds__(256) void bucket_expand2(
    const unsigned* __restrict__ pairsA, const int* __restrict__ bbaseA, int nA,
    int* __restrict__ offA, int* __restrict__ csrA, int shA, int nbA,
    const unsigned* __restrict__ pairsB, const int* __restrict__ bbaseB, int nB,
    int* __restrict__ offB, int* __restrict__ csrB, int shB, int srcbits) {
    __shared__ int lcnt[1024];
    __shared__ int red[256];
    const unsigned* pairs; const int* bbase; int n; int* off; int* csr; int sh; int b;
    if ((int)blockIdx.x < nbA) {
        pairs = pairsA; bbase = bbaseA; n = nA; off = offA; csr = csrA; sh = shA;
        b = blockIdx.x;
    } else {
        pairs = pairsB; bbase = bbaseB; n = nB; off = offB; csr = csrB; sh = shB;
        b = blockIdx.x - nbA;
    }
    int dpb = 1 << sh;
    int d0 = b << sh;
    int t = threadIdx.x;
    unsigned smask = (1u << srcbits) - 1u;
    for (int dl = t; dl < dpb; dl += 256) lcnt[dl] = 0;
    __syncthreads();
    int pbeg = bbase[b], pend = bbase[b + 1];
    for (int i = pbeg + t; i < pend; i += 256)
        atomicAdd(&lcnt[pairs[i] >> srcbits], 1);
    __syncthreads();
    int per = (dpb + 255) >> 8;
    int i0 = t * per;
    int s = 0;
    for (int j = 0; j < per; ++j) {
        int dl = i0 + j;
        if (dl < dpb) s += lcnt[dl];
    }
    red[t] = s;
    __syncthreads();
    for (int st = 1; st < 256; st <<= 1) {
        int tmp = (t >= st) ? red[t - st] : 0;
        __syncthreads();
        red[t] += tmp;
        __syncthreads();
    }
    int run = pbeg + red[t] - s;
    for (int j = 0; j < per; ++j) {
        int dl = i0 + j;
        if (dl < dpb) {
            int c = lcnt[dl];
            if (d0 + dl < n) off[d0 + dl] = run;
            lcnt[dl] = run;
            run += c;
        }
    }
    __syncthreads();
    for (int i = pbeg + t; i < pend; i += 256) {
        unsigned p = pairs[i];
        int dl = (int)(p >> srcbits);
        int pos = atomicAdd(&lcnt[dl], 1);
        csr[pos] = (int)(p & smask);
    }
}

// ========== fragment-ordered W pack — all 4 matrices in ONE launch ==========
// Wp[((ct*NKB+kb)*64 + (lr+16*lk))*8 + e] = W^T[ct*16+lr][kb*32+lk*8+e]
__global__ __launch_bounds__(256) void pack_w_all(
    const float* __restrict__ Wa0, const float* __restrict__ Wb0, _Float16* __restrict__ P0,
    const float* __restrict__ Wa1, const float* __restrict__ Wb1, _Float16* __restrict__ P1,
    const float* __restrict__ Wa2, const float* __restrict__ Wb2, _Float16* __restrict__ P2,
    const float* __restrict__ Wa3, const float* __restrict__ Wb3, _Float16* __restrict__ P3) {
    int b = blockIdx.x;
    const float* Wa; const float* Wb; _Float16* Wp; int K; int lb;
    if (b < 64)       { Wa = Wa0; Wb = Wb0; Wp = P0; K = 128; lb = b; }
    else if (b < 128) { Wa = Wa1; Wb = Wb1; Wp = P1; K = 128; lb = b - 64; }
    else if (b < 160) { Wa = Wa2; Wb = Wb2; Wp = P2; K = 64;  lb = b - 128; }
    else              { Wa = Wa3; Wb = Wb3; Wp = P3; K = 64;  lb = b - 160; }
    int NKB = K / 32;
    int i = lb * 256 + threadIdx.x;
    if (i >= 128 * K) return;
    int k = i >> 7, c = i & 127;
    float v = (c < 64) ? Wa[k * 64 + c] : Wb[k * 64 + (c - 64)];
    int ct = c >> 4, lr = c & 15, kb = k >> 5, lk = (k & 31) >> 3, e = k & 7;
    Wp[((ct * NKB + kb) * 64 + (lr + 16 * lk)) * 8 + e] = (_Float16)v;
}

// ================= MFMA dual projection v3: zero-conflict LDS, X direct-to-reg ========
template <int K, typename TIN>
__global__ __launch_bounds__(256) void proj_mfma3_kernel(const TIN* __restrict__ X, int N,
                                                         const _Float16* __restrict__ Wp,
                                                         const float* __restrict__ a0v,
                                                         const float* __restrict__ a1v,
                                                         __half* __restrict__ out0,
                                                         float* __restrict__ al0,
                                                         float* __restrict__ al1) {
    constexpr int NKB = K / 32;
    __shared__ __align__(16) _Float16 Wlds[128 * K];
    int t = threadIdx.x;
    constexpr int NV = (128 * K) / 8;
#pragma unroll
    for (int i = t; i < NV; i += 256)
        ((uint4*)Wlds)[i] = ((const uint4*)Wp)[i];
    __syncthreads();

    int rt = blockIdx.x * 64;
    int wv = t >> 6, lane = t & 63, lr = lane & 15, lk = lane >> 4;
    int row = rt + wv * 16 + lr;
    int rowc = row < N ? row : N - 1;

    f32x4 acc[8];
#pragma unroll
    for (int i = 0; i < 8; ++i) acc[i] = f32x4{0.f, 0.f, 0.f, 0.f};

    const f16x8* Wf = (const f16x8*)Wlds;
#pragma unroll
    for (int kb = 0; kb < NKB; ++kb) {
        f16x8 bf;
        if constexpr (sizeof(TIN) == 4) {
            const float* xr = (const float*)X + (size_t)rowc * K + kb * 32 + lk * 8;
            float4 x0 = *(const float4*)xr;
            float4 x1 = *(const float4*)(xr + 4);
            bf[0] = (_Float16)x0.x; bf[1] = (_Float16)x0.y;
            bf[2] = (_Float16)x0.z; bf[3] = (_Float16)x0.w;
            bf[4] = (_Float16)x1.x; bf[5] = (_Float16)x1.y;
            bf[6] = (_Float16)x1.z; bf[7] = (_Float16)x1.w;
        } else {
            bf = *(const f16x8*)((const _Float16*)X + (size_t)rowc * K + kb * 32 + lk * 8);
        }
#pragma unroll
        for (int ct = 0; ct < 8; ++ct) {
            acc[ct] = __builtin_amdgcn_mfma_f32_16x16x32_f16(Wf[(ct * NKB + kb) * 64 + lane],
                                                             bf, acc[ct], 0, 0, 0);
        }
    }

    float p0 = 0.f, p1 = 0.f;
#pragma unroll
    for (int ct = 0; ct < 4; ++ct) {
        float4 aq = ((const float4*)a0v)[ct * 4 + lk];
        f32x4 v = acc[ct];
        p0 += v[0] * aq.x + v[1] * aq.y + v[2] * aq.z + v[3] * aq.w;
    }
#pragma unroll
    for (int ct = 0; ct < 4; ++ct) {
        float4 aq = ((const float4*)a1v)[ct * 4 + lk];
        f32x4 v = acc[4 + ct];
        p1 += v[0] * aq.x + v[1] * aq.y + v[2] * aq.z + v[3] * aq.w;
    }
    p0 += __shfl_xor(p0, 16); p0 += __shfl_xor(p0, 32);
    p1 += __shfl_xor(p1, 16); p1 += __shfl_xor(p1, 32);
    if (row < N) {
#pragma unroll
        for (int ct = 0; ct < 4; ++ct) {
            f32x4 v = acc[ct];
            __half2 h01 = __floats2half2_rn(v[0], v[1]);
            __half2 h23 = __floats2half2_rn(v[2], v[3]);
            uint2 pk;
            pk.x = *(const unsigned int*)&h01;
            pk.y = *(const unsigned int*)&h23;
            *(uint2*)(out0 + ((size_t)row << 6) + ct * 16 + lk * 4) = pk;
        }
        if (lane < 16) { al0[row] = p0; al1[row] = p1; }
    }
}

// ========== GAT aggregation v8: 16-lane group/dst, padded small LDS, 8-deep gathers ======
// exp(alpha-8) == softmax-identical (no max pass). CAP=64 (deg ~ Poisson(<=20): P(>64)~1e-13;
// exact fallback re-gathers the tail). Pad 66 -> group stride 528B -> banks spread, ~2-way.
// Low VGPR + 8.4KB LDS -> full 32-wave/CU residency (latency hiding via TLP).
#define AGG_CAP 64
#define AGG_PAD 66

template <int RELU, int HALF_OUT>
__global__ __launch_bounds__(256) void gat_aggregate8(
    const int* __restrict__ off0, const int* __restrict__ csr0,
    const __half* __restrict__ hs0, const float* __restrict__ als0,
    const float* __restrict__ ald0, const float* __restrict__ bias0,
    void* __restrict__ outp0, int n0,
    const int* __restrict__ off1, const int* __restrict__ csr1,
    const __half* __restrict__ hs1, const float* __restrict__ als1,
    const float* __restrict__ ald1, const float* __restrict__ bias1,
    void* __restrict__ outp1, int n1,
    int nb0) {
    __shared__ uint2 wP[16][AGG_PAD];
    int t = threadIdx.x;
    int slot = t >> 4;
    int sub = t & 15;

    const int* off; const int* csr; const __half* hs; const float* als;
    const float* ald; const float* bias; void* outp; int nd; int b;
    if (blockIdx.x < (unsigned)nb0) {
        b = blockIdx.x;
        off = off0; csr = csr0; hs = hs0; als = als0; ald = ald0; bias = bias0;
        outp = outp0; nd = n0;
    } else {
        b = blockIdx.x - nb0;
        off = off1; csr = csr1; hs = hs1; als = als1; ald = ald1; bias = bias1;
        outp = outp1; nd = n1;
    }
    int d = b * 16 + slot;
    bool active = d < nd;
    int beg = 0, deg = 0;
    float aldv = 0.f;
    if (active) {
        beg = off[d];
        deg = off[d + 1] - beg;
        aldv = ald[d];
    }
    float4 bl4 = ((const float4*)bias)[sub];
    uint2* WP = wP[slot];

    // pass 1: weights + denom (16-lane stripe)
    float sum = 0.f;
    for (int i = sub; i < deg; i += 16) {
        int s = csr[beg + i];
        float a = als[s] + aldv;
        a = (a >= 0.f) ? a : 0.2f * a;
        float w = exp_am8(a);
        sum += w;
        if (i < AGG_CAP) {
            __half hw = __float2half_rn(w);
            __half2 h2 = __half2half2(hw);
            WP[i] = make_uint2(*(const unsigned int*)&h2, (unsigned int)s);
        }
    }
    sum += __shfl_xor(sum, 1);
    sum += __shfl_xor(sum, 2);
    sum += __shfl_xor(sum, 4);
    sum += __shfl_xor(sum, 8);
    float inv = 1.f / fmaxf(sum, 1e-16f);

    // pass 2: 4 channels/lane; 8-deep then 2-step then remainder
    int dc = deg < AGG_CAP ? deg : AGG_CAP;
    const uint2* hs4 = (const uint2*)hs;   // row = 16 x uint2 (64 ch)
    __half2 z = __floats2half2_rn(0.f, 0.f);
    __half2 aA = z, aB = z, aC = z, aD = z;
    int i = 0;
    for (; i + 8 <= dc; i += 8) {
        uint4 q0 = *(const uint4*)&WP[i];
        uint4 q1 = *(const uint4*)&WP[i + 2];
        uint4 q2 = *(const uint4*)&WP[i + 4];
        uint4 q3 = *(const uint4*)&WP[i + 6];
        uint2 v0 = hs4[(size_t)q0.y * 16 + sub];
        uint2 v1 = hs4[(size_t)q0.w * 16 + sub];
        uint2 v2 = hs4[(size_t)q1.y * 16 + sub];
        uint2 v3 = hs4[(size_t)q1.w * 16 + sub];
        uint2 v4 = hs4[(size_t)q2.y * 16 + sub];
        uint2 v5 = hs4[(size_t)q2.w * 16 + sub];
        uint2 v6 = hs4[(size_t)q3.y * 16 + sub];
        uint2 v7 = hs4[(size_t)q3.w * 16 + sub];
        aA = __hfma2(*(const __half2*)&q0.x, *(const __half2*)&v0.x, aA);
        aB = __hfma2(*(const __half2*)&q0.x, *(const __half2*)&v0.y, aB);
        aC = __hfma2(*(const __half2*)&q0.z, *(const __half2*)&v1.x, aC);
        aD = __hfma2(*(const __half2*)&q0.z, *(const __half2*)&v1.y, aD);
        aA = __hfma2(*(const __half2*)&q1.x, *(const __half2*)&v2.x, aA);
        aB = __hfma2(*(const __half2*)&q1.x, *(const __half2*)&v2.y, aB);
        aC = __hfma2(*(const __half2*)&q1.z, *(const __half2*)&v3.x, aC);
        aD = __hfma2(*(const __half2*)&q1.z, *(const __half2*)&v3.y, aD);
        aA = __hfma2(*(const __half2*)&q2.x, *(const __half2*)&v4.x, aA);
        aB = __hfma2(*(const __half2*)&q2.x, *(const __half2*)&v4.y, aB);
        aC = __hfma2(*(const __half2*)&q2.z, *(const __half2*)&v5.x, aC);
        aD = __hfma2(*(const __half2*)&q2.z, *(const __half2*)&v5.y, aD);
        aA = __hfma2(*(const __half2*)&q3.x, *(const __half2*)&v6.x, aA);
        aB = __hfma2(*(const __half2*)&q3.x, *(const __half2*)&v6.y, aB);
        aC = __hfma2(*(const __half2*)&q3.z, *(const __half2*)&v7.x, aC);
        aD = __hfma2(*(const __half2*)&q3.z, *(const __half2*)&v7.y, aD);
    }
    for (; i + 2 <= dc; i += 2) {
        uint4 q = *(const uint4*)&WP[i];
        uint2 v0 = hs4[(size_t)q.y * 16 + sub];
        uint2 v1 = hs4[(size_t)q.w * 16 + sub];
        aA = __hfma2(*(const __half2*)&q.x, *(const __half2*)&v0.x, aA);
        aB = __hfma2(*(const __half2*)&q.x, *(const __half2*)&v0.y, aB);
        aC = __hfma2(*(const __half2*)&q.z, *(const __half2*)&v1.x, aC);
        aD = __hfma2(*(const __half2*)&q.z, *(const __half2*)&v1.y, aD);
    }
    if (i < dc) {
        uint2 u = WP[i];
        uint2 v = hs4[(size_t)u.y * 16 + sub];
        aA = __hfma2(*(const __half2*)&u.x, *(const __half2*)&v.x, aA);
        aB = __hfma2(*(const __half2*)&u.x, *(const __half2*)&v.y, aB);
    }
    // exact fallback for deg > AGG_CAP (recompute weight)
    for (int j = AGG_CAP; j < deg; ++j) {
        int s = csr[beg + j];
        float a = als[s] + aldv;
        a = (a >= 0.f) ? a : 0.2f * a;
        __half hw = __float2half_rn(exp_am8(a));
        __half2 w2 = __half2half2(hw);
        uint2 v = hs4[(size_t)s * 16 + sub];
        aA = __hfma2(w2, *(const __half2*)&v.x, aA);
        aB = __hfma2(w2, *(const __half2*)&v.y, aB);
    }
    float2 fA = __half22float2(aA);
    float2 fB = __half22float2(aB);
    float2 fC = __half22float2(aC);
    float2 fD = __half22float2(aD);
    float o0 = (fA.x + fC.x) * inv + bl4.x;
    float o1 = (fA.y + fC.y) * inv + bl4.y;
    float o2 = (fB.x + fD.x) * inv + bl4.z;
    float o3 = (fB.y + fD.y) * inv + bl4.w;
    if (deg == 0) { o0 = bl4.x; o1 = bl4.y; o2 = bl4.z; o3 = bl4.w; }
    if (RELU) {
        o0 = fmaxf(o0, 0.f); o1 = fmaxf(o1, 0.f);
        o2 = fmaxf(o2, 0.f); o3 = fmaxf(o3, 0.f);
    }
    if (active) {
        if (HALF_OUT) {
            __half2 h01 = __floats2half2_rn(o0, o1);
            __half2 h23 = __floats2half2_rn(o2, o3);
            uint2 pk;
            pk.x = *(const unsigned int*)&h01;
            pk.y = *(const unsigned int*)&h23;
            ((uint2*)outp)[(size_t)d * 16 + sub] = pk;
        } else {
            ((float4*)outp)[(size_t)d * 16 + sub] = make_float4(o0, o1, o2, o3);
        }
    }
}

// ---------------- decoder (inline Wc = Wd1@Wd2 prep per block) ----------------
__global__ __launch_bounds__(256) void decoder3_kernel(const int* __restrict__ row,
                                                       const int* __restrict__ col,
                                                       const __half* __restrict__ zm2,
                                                       const __half* __restrict__ zc2,
                                                       const float* __restrict__ Wd1,
                                                       const float* __restrict__ bd1,
                                                       const float* __restrict__ Wd2,
                                                       const float* __restrict__ bd2,
                                                       float* __restrict__ out, int EL) {
    __shared__ float WcL[256];
    __shared__ float bcL[2];
    int t = threadIdx.x;
    {
        int k = t >> 1, c = t & 1;
        float s = 0.f;
        for (int j = 0; j < 64; ++j) s += Wd1[k * 64 + j] * Wd2[j * 2 + c];
        WcL[k * 2 + c] = s;
        if (t < 2) {
            float bv = bd2[t];
            for (int j = 0; j < 64; ++j) bv += bd1[j] * Wd2[j * 2 + t];
            bcL[t] = bv;
        }
    }
    __syncthreads();
    int lane = t & 63;
    int sub = lane & 31;
    int hw = (blockIdx.x * 256 + t) >> 5;
    int nhw = (gridDim.x * 256) >> 5;
    float4 wA = ((const float4*)WcL)[sub];
    float4 wB = ((const float4*)WcL)[32 + sub];
    float b0 = bcL[0], b1 = bcL[1];
    const __half2* zmh = (const __half2*)zm2;
    const __half2* zch = (const __half2*)zc2;
    for (int e = hw; e < EL; e += nhw) {
        int r = row[e], c = col[e];
        float2 f = __half22float2(zmh[((size_t)r << 5) + sub]);
        float2 g = __half22float2(zch[((size_t)c << 5) + sub]);
        float p0 = f.x * wA.x + f.y * wA.z + g.x * wB.x + g.y * wB.z;
        float p1 = f.x * wA.y + f.y * wA.w + g.x * wB.y + g.y * wB.w;
        p0 += __shfl_xor(p0, 1);  p1 += __shfl_xor(p1, 1);
        p0 += __shfl_xor(p0, 2);  p1 += __shfl_xor(p1, 2);
        p0 += __shfl_xor(p0, 4);  p1 += __shfl_xor(p1, 4);
        p0 += __shfl_xor(p0, 8);  p1 += __shfl_xor(p1, 8);
        p0 += __shfl_xor(p0, 16); p1 += __shfl_xor(p1, 16);
        if (sub == 0) *(float2*)(out + 2 * (size_t)e) = make_float2(p0 + b0, p1 + b1);
    }
}

// ---------------- launch ----------------
extern "C" void kernel_launch(void* const* d_in, const int* in_sizes, int n_in,
                              void* d_out, int out_size, void* d_ws, size_t ws_size,
                              hipStream_t stream) {
    const int D = 128;
    const float* x_m    = (const float*)d_in[0];
    const float* x_c    = (const float*)d_in[1];
    const int*   src_mc = (const int*)d_in[2];
    const int*   dst_mc = (const int*)d_in[3];
    const int*   src_cm = (const int*)d_in[4];
    const int*   dst_cm = (const int*)d_in[5];
    const int*   rowi   = (const int*)d_in[6];
    const int*   coli   = (const int*)d_in[7];
    const float* W1s_mc = (const float*)d_in[8];
    const float* W1d_mc = (const float*)d_in[9];
    const float* a1s_mc = (const float*)d_in[10];
    const float* a1d_mc = (const float*)d_in[11];
    const float* b1_mc  = (const float*)d_in[12];
    const float* W1s_cm = (const float*)d_in[13];
    const float* W1d_cm = (const float*)d_in[14];
    const float* a1s_cm = (const float*)d_in[15];
    const float* a1d_cm = (const float*)d_in[16];
    const float* b1_cm  = (const float*)d_in[17];
    const float* W2s_mc = (const float*)d_in[18];
    const float* W2d_mc = (const float*)d_in[19];
    const float* a2s_mc = (const float*)d_in[20];
    const float* a2d_mc = (const float*)d_in[21];
    const float* b2_mc  = (const float*)d_in[22];
    const float* W2s_cm = (const float*)d_in[23];
    const float* W2d_cm = (const float*)d_in[24];
    const float* a2s_cm = (const float*)d_in[25];
    const float* a2d_cm = (const float*)d_in[26];
    const float* b2_cm  = (const float*)d_in[27];
    const float* Wd1    = (const float*)d_in[28];
    const float* bd1    = (const float*)d_in[29];
    const float* Wd2    = (const float*)d_in[30];
    const float* bd2    = (const float*)d_in[31];

    const int N_M = in_sizes[0] / D;
    const int N_C = in_sizes[1] / D;
    const int E   = in_sizes[2];
    const int EL  = in_sizes[6];
    float* out = (float*)d_out;

    uint8_t* base = (uint8_t*)d_ws;
    size_t off = 0;
    auto carve = [&](size_t bytes) -> void* {
        void* p = base + off;
        off += (bytes + 255) & ~(size_t)255;
        return p;
    };
    __half* hsA_h = (__half*)carve((size_t)N_M * 64 * 2);
    __half* hsB_h = (__half*)carve((size_t)N_C * 64 * 2);
    __half* zm1_h = (__half*)carve((size_t)N_M * 64 * 2);
    __half* zc1_h = (__half*)carve((size_t)N_C * 64 * 2);
    __half* zm2_h = (__half*)carve((size_t)N_M * 64 * 2);
    __half* zc2_h = (__half*)carve((size_t)N_C * 64 * 2);
    float* als_mc = (float*)carve((size_t)N_M * 4);
    float* ald_cm = (float*)carve((size_t)N_M * 4);
    float* als_cm = (float*)carve((size_t)N_C * 4);
    float* ald_mc = (float*)carve((size_t)N_C * 4);
    int* off_mc = (int*)carve((size_t)(N_C + 1) * 4);
    int* off_cm = (int*)carve((size_t)(N_M + 1) * 4);
    int* csr_mc = (int*)carve((size_t)E * 4);
    int* csr_cm = (int*)carve((size_t)E * 4);
    unsigned* pairs_mc = (unsigned*)carve((size_t)E * 4);
    unsigned* pairs_cm = (unsigned*)carve((size_t)E * 4);
    int* bcnt_base = (int*)carve(512 * 4);
    int* bcnt_mc = bcnt_base;
    int* bcnt_cm = bcnt_base + 256;
    int* bbase_mc = (int*)carve(257 * 4);
    int* bbase_cm = (int*)carve(257 * 4);
    int* bcur_mc = (int*)carve(256 * 4);
    int* bcur_cm = (int*)carve(256 * 4);
    _Float16* wp1A = (_Float16*)carve(128 * 128 * 2);
    _Float16* wp1B = (_Float16*)carve(128 * 128 * 2);
    _Float16* wp2A = (_Float16*)carve(128 * 64 * 2);
    _Float16* wp2B = (_Float16*)carve(128 * 64 * 2);

    int shA = 0; while (((N_C + (1 << shA) - 1) >> shA) > 256) shA++;
    int shB = 0; while (((N_M + (1 << shB) - 1) >> shB) > 256) shB++;
    int nbkA = (N_C + (1 << shA) - 1) >> shA;
    int nbkB = (N_M + (1 << shB) - 1) >> shB;
    int maxN = N_M > N_C ? N_M : N_C;
    int srcbits = 1; while ((1 << srcbits) < maxN) srcbits++;

    // ---- W fragment pre-pack (single launch) ----
    pack_w_all<<<192, 256, 0, stream>>>(W1s_mc, W1d_cm, wp1A,
                                        W1s_cm, W1d_mc, wp1B,
                                        W2s_mc, W2d_cm, wp2A,
                                        W2s_cm, W2d_mc, wp2B);

    // ---- CSR build (bucket-first) ----
    hipMemsetAsync(bcnt_base, 0, 512 * 4, stream);
    int nblk = (E + 4095) / 4096;
    bucket_hist<<<2 * nblk, 256, 0, stream>>>(dst_mc, bcnt_mc, shA,
                                              dst_cm, bcnt_cm, shB, E, nblk);
    bucket_scan<<<1, 128, 0, stream>>>(bcnt_mc, nbkA, bbase_mc, bcur_mc, off_mc, N_C,
                                       bcnt_cm, nbkB, bbase_cm, bcur_cm, off_cm, N_M, E);
    bucket_scatter<<<2 * nblk, 256, 0, stream>>>(
        src_mc, dst_mc, bcur_mc, pairs_mc,
        src_cm, dst_cm, bcur_cm, pairs_cm, E, nblk, shA, shB, srcbits);
    bucket_expand2<<<nbkA + nbkB, 256, 0, stream>>>(
        pairs_mc, bbase_mc, N_C, off_mc, csr_mc, shA, nbkA,
        pairs_cm, bbase_cm, N_M, off_cm, csr_cm, shB, srcbits);

    int nb_c = (N_C + 15) / 16;
    int nb_m = (N_M + 15) / 16;

    // ---- Layer 1 (f32 inputs -> fp16 MFMA) ----
    proj_mfma3_kernel<128, float><<<(N_M + 63) / 64, 256, 0, stream>>>(
        x_m, N_M, wp1A, a1s_mc, a1d_cm, hsA_h, als_mc, ald_cm);
    proj_mfma3_kernel<128, float><<<(N_C + 63) / 64, 256, 0, stream>>>(
        x_c, N_C, wp1B, a1s_cm, a1d_mc, hsB_h, als_cm, ald_mc);
    gat_aggregate8<1, 1><<<nb_c + nb_m, 256, 0, stream>>>(
        off_mc, csr_mc, hsA_h, als_mc, ald_mc, b1_mc, zc1_h, N_C,
        off_cm, csr_cm, hsB_h, als_cm, ald_cm, b1_cm, zm1_h, N_M, nb_c);

    // ---- Layer 2 (fp16 inputs) ----
    proj_mfma3_kernel<64, __half><<<(N_M + 63) / 64, 256, 0, stream>>>(
        zm1_h, N_M, wp2A, a2s_mc, a2d_cm, hsA_h, als_mc, ald_cm);
    proj_mfma3_kernel<64, __half><<<(N_C + 63) / 64, 256, 0, stream>>>(
        zc1_h, N_C, wp2B, a2s_cm, a2d_mc, hsB_h, als_cm, ald_mc);
    gat_aggregate8<0, 1><<<nb_c + nb_m, 256, 0, stream>>>(
        off_mc, csr_mc, hsA_h, als_mc, ald_mc, b2_mc, zc2_h, N_C,
        off_cm, csr_cm, hsB_h, als_cm, ald_cm, b2_cm, zm2_h, N_M, nb_c);

    // ---- Decoder ----
    decoder3_kernel<<<2048, 256, 0, stream>>>(rowi, coli, zm2_h, zc2_h,
                                              Wd1, bd1, Wd2, bd2, out, EL);
}

// Round 19
// 261.581 us; speedup vs baseline: 1.1074x; 1.0442x over previous
//
#include <hip/hip_runtime.h>
#include <hip/hip_fp16.h>
#include <cstdint>
#include <cstddef>

typedef _Float16 f16x8 __attribute__((ext_vector_type(8)));
typedef float f32x4 __attribute__((ext_vector_type(4)));

__device__ __forceinline__ float exp_am8(float a) {
    // exp(a-8) == 2^(a*log2e - 8*log2e); single v_exp_f32
    return __builtin_amdgcn_exp2f(fmaf(a, 1.442695040888963f, -11.541560327111707f));
}

// ================= CSR build: bucket-first, no per-dst global histogram =================
__global__ __launch_bounds__(256) void bucket_hist(const int* __restrict__ dA,
                                                   int* __restrict__ bcntA, int shA,
                                                   const int* __restrict__ dB,
                                                   int* __restrict__ bcntB, int shB,
                                                   int E, int nblkA) {
    __shared__ int h[256];
    const int* dst; int* bcnt; int sh; int base;
    if ((int)blockIdx.x < nblkA) { dst = dA; bcnt = bcntA; sh = shA; base = blockIdx.x * 4096; }
    else { dst = dB; bcnt = bcntB; sh = shB; base = (blockIdx.x - nblkA) * 4096; }
    int t = threadIdx.x;
    h[t] = 0;
    __syncthreads();
#pragma unroll
    for (int j = 0; j < 16; ++j) {
        int i = base + j * 256 + t;
        if (i < E) atomicAdd(&h[dst[i] >> sh], 1);
    }
    __syncthreads();
    int c = h[t];
    if (c > 0) atomicAdd(&bcnt[t], c);
}

__global__ void bucket_scan(const int* __restrict__ bcntA, int nbkA,
                            int* __restrict__ bbaseA, int* __restrict__ bcurA,
                            int* __restrict__ offA, int nA,
                            const int* __restrict__ bcntB, int nbkB,
                            int* __restrict__ bbaseB, int* __restrict__ bcurB,
                            int* __restrict__ offB, int nB, int E) {
    int t = threadIdx.x;
    if (t == 0) {
        int run = 0;
        for (int i = 0; i < nbkA; ++i) { bbaseA[i] = run; bcurA[i] = run; run += bcntA[i]; }
        bbaseA[nbkA] = run;
        offA[nA] = E;
    }
    if (t == 64) {
        int run = 0;
        for (int i = 0; i < nbkB; ++i) { bbaseB[i] = run; bcurB[i] = run; run += bcntB[i]; }
        bbaseB[nbkB] = run;
        offB[nB] = E;
    }
}

__global__ __launch_bounds__(256) void bucket_scatter(
    const int* __restrict__ srcA, const int* __restrict__ dstA,
    int* __restrict__ bcurA, unsigned* __restrict__ pairsA,
    const int* __restrict__ srcB, const int* __restrict__ dstB,
    int* __restrict__ bcurB, unsigned* __restrict__ pairsB,
    int E, int nblkA, int shA, int shB, int srcbits) {
    __shared__ int bcnt[256];
    __shared__ int bbase[256];
    const int* src; const int* dst; int* bcur; unsigned* pairs; int sh; int base;
    if ((int)blockIdx.x < nblkA) {
        src = srcA; dst = dstA; bcur = bcurA; pairs = pairsA; sh = shA;
        base = blockIdx.x * 4096;
    } else {
        src = srcB; dst = dstB; bcur = bcurB; pairs = pairsB; sh = shB;
        base = (blockIdx.x - nblkA) * 4096;
    }
    int t = threadIdx.x;
    int msk = (1 << sh) - 1;
    bcnt[t] = 0;
    __syncthreads();
    int sreg[16], dreg[16];
#pragma unroll
    for (int j = 0; j < 16; ++j) {
        int i = base + j * 256 + t;
        if (i < E) {
            sreg[j] = src[i];
            dreg[j] = dst[i];
            atomicAdd(&bcnt[dreg[j] >> sh], 1);
        } else {
            dreg[j] = -1;
        }
    }
    __syncthreads();
    {
        int c = bcnt[t];
        int g = (c > 0) ? atomicAdd(&bcur[t], c) : 0;
        bbase[t] = g;
        bcnt[t] = 0;
    }
    __syncthreads();
#pragma unroll
    for (int j = 0; j < 16; ++j) {
        if (dreg[j] >= 0) {
            int b = dreg[j] >> sh;
            int r = atomicAdd(&bcnt[b], 1);
            pairs[bbase[b] + r] = ((unsigned)(dreg[j] & msk) << srcbits) | (unsigned)sreg[j];
        }
    }
}

__global__ __launch_bounds__(256) void bucket_expand2(
    const unsigned* __restrict__ pairsA, const int* __restrict__ bbaseA, int nA,
    int* __restrict__ offA, int* __restrict__ csrA, int shA, int nbA,
    const unsigned* __restrict__ pairsB, const int* __restrict__ bbaseB, int nB,
    int* __restrict__ offB, int* __restrict__ csrB, int shB, int srcbits) {
    __shared__ int lcnt[1024];
    __shared__ int red[256];
    const unsigned* pairs; const int* bbase; int n; int* off; int* csr; int sh; int b;
    if ((int)blockIdx.x < nbA) {
        pairs = pairsA; bbase = bbaseA; n = nA; off = offA; csr = csrA; sh = shA;
        b = blockIdx.x;
    } else {
        pairs = pairsB; bbase = bbaseB; n = nB; off = offB; csr = csrB; sh = shB;
        b = blockIdx.x - nbA;
    }
    int dpb = 1 << sh;
    int d0 = b << sh;
    int t = threadIdx.x;
    unsigned smask = (1u << srcbits) - 1u;
    for (int dl = t; dl < dpb; dl += 256) lcnt[dl] = 0;
    __syncthreads();
    int pbeg = bbase[b], pend = bbase[b + 1];
    for (int i = pbeg + t; i < pend; i += 256)
        atomicAdd(&lcnt[pairs[i] >> srcbits], 1);
    __syncthreads();
    int per = (dpb + 255) >> 8;
    int i0 = t * per;
    int s = 0;
    for (int j = 0; j < per; ++j) {
        int dl = i0 + j;
        if (dl < dpb) s += lcnt[dl];
    }
    red[t] = s;
    __syncthreads();
    for (int st = 1; st < 256; st <<= 1) {
        int tmp = (t >= st) ? red[t - st] : 0;
        __syncthreads();
        red[t] += tmp;
        __syncthreads();
    }
    int run = pbeg + red[t] - s;
    for (int j = 0; j < per; ++j) {
        int dl = i0 + j;
        if (dl < dpb) {
            int c = lcnt[dl];
            if (d0 + dl < n) off[d0 + dl] = run;
            lcnt[dl] = run;
            run += c;
        }
    }
    __syncthreads();
    for (int i = pbeg + t; i < pend; i += 256) {
        unsigned p = pairs[i];
        int dl = (int)(p >> srcbits);
        int pos = atomicAdd(&lcnt[dl], 1);
        csr[pos] = (int)(p & smask);
    }
}

// ========== fragment-ordered W pack — all 4 matrices in ONE launch ==========
__global__ __launch_bounds__(256) void pack_w_all(
    const float* __restrict__ Wa0, const float* __restrict__ Wb0, _Float16* __restrict__ P0,
    const float* __restrict__ Wa1, const float* __restrict__ Wb1, _Float16* __restrict__ P1,
    const float* __restrict__ Wa2, const float* __restrict__ Wb2, _Float16* __restrict__ P2,
    const float* __restrict__ Wa3, const float* __restrict__ Wb3, _Float16* __restrict__ P3) {
    int b = blockIdx.x;
    const float* Wa; const float* Wb; _Float16* Wp; int K; int lb;
    if (b < 64)       { Wa = Wa0; Wb = Wb0; Wp = P0; K = 128; lb = b; }
    else if (b < 128) { Wa = Wa1; Wb = Wb1; Wp = P1; K = 128; lb = b - 64; }
    else if (b < 160) { Wa = Wa2; Wb = Wb2; Wp = P2; K = 64;  lb = b - 128; }
    else              { Wa = Wa3; Wb = Wb3; Wp = P3; K = 64;  lb = b - 160; }
    int NKB = K / 32;
    int i = lb * 256 + threadIdx.x;
    if (i >= 128 * K) return;
    int k = i >> 7, c = i & 127;
    float v = (c < 64) ? Wa[k * 64 + c] : Wb[k * 64 + (c - 64)];
    int ct = c >> 4, lr = c & 15, kb = k >> 5, lk = (k & 31) >> 3, e = k & 7;
    Wp[((ct * NKB + kb) * 64 + (lr + 16 * lk)) * 8 + e] = (_Float16)v;
}

// ---------------- decoder prep: Wc = Wd1@Wd2 [128,2]; bc = bd1@Wd2 + bd2 ----------------
__global__ void decoder_prep(const float* __restrict__ Wd1, const float* __restrict__ bd1,
                             const float* __restrict__ Wd2, const float* __restrict__ bd2,
                             float* __restrict__ Wc, float* __restrict__ bc) {
    int t = threadIdx.x;
    int k = t >> 1, c = t & 1;
    float s = 0.f;
    for (int j = 0; j < 64; ++j) s += Wd1[k * 64 + j] * Wd2[j * 2 + c];
    Wc[k * 2 + c] = s;
    if (k == 0) {
        float b = bd2[c];
        for (int j = 0; j < 64; ++j) b += bd1[j] * Wd2[j * 2 + c];
        bc[c] = b;
    }
}

// ================= MFMA dual projection v3: zero-conflict LDS, X direct-to-reg ========
template <int K, typename TIN>
__global__ __launch_bounds__(256) void proj_mfma3_kernel(const TIN* __restrict__ X, int N,
                                                         const _Float16* __restrict__ Wp,
                                                         const float* __restrict__ a0v,
                                                         const float* __restrict__ a1v,
                                                         __half* __restrict__ out0,
                                                         float* __restrict__ al0,
                                                         float* __restrict__ al1) {
    constexpr int NKB = K / 32;
    __shared__ __align__(16) _Float16 Wlds[128 * K];
    int t = threadIdx.x;
    constexpr int NV = (128 * K) / 8;
#pragma unroll
    for (int i = t; i < NV; i += 256)
        ((uint4*)Wlds)[i] = ((const uint4*)Wp)[i];
    __syncthreads();

    int rt = blockIdx.x * 64;
    int wv = t >> 6, lane = t & 63, lr = lane & 15, lk = lane >> 4;
    int row = rt + wv * 16 + lr;
    int rowc = row < N ? row : N - 1;

    f32x4 acc[8];
#pragma unroll
    for (int i = 0; i < 8; ++i) acc[i] = f32x4{0.f, 0.f, 0.f, 0.f};

    const f16x8* Wf = (const f16x8*)Wlds;
#pragma unroll
    for (int kb = 0; kb < NKB; ++kb) {
        f16x8 bf;
        if constexpr (sizeof(TIN) == 4) {
            const float* xr = (const float*)X + (size_t)rowc * K + kb * 32 + lk * 8;
            float4 x0 = *(const float4*)xr;
            float4 x1 = *(const float4*)(xr + 4);
            bf[0] = (_Float16)x0.x; bf[1] = (_Float16)x0.y;
            bf[2] = (_Float16)x0.z; bf[3] = (_Float16)x0.w;
            bf[4] = (_Float16)x1.x; bf[5] = (_Float16)x1.y;
            bf[6] = (_Float16)x1.z; bf[7] = (_Float16)x1.w;
        } else {
            bf = *(const f16x8*)((const _Float16*)X + (size_t)rowc * K + kb * 32 + lk * 8);
        }
#pragma unroll
        for (int ct = 0; ct < 8; ++ct) {
            acc[ct] = __builtin_amdgcn_mfma_f32_16x16x32_f16(Wf[(ct * NKB + kb) * 64 + lane],
                                                             bf, acc[ct], 0, 0, 0);
        }
    }

    float p0 = 0.f, p1 = 0.f;
#pragma unroll
    for (int ct = 0; ct < 4; ++ct) {
        float4 aq = ((const float4*)a0v)[ct * 4 + lk];
        f32x4 v = acc[ct];
        p0 += v[0] * aq.x + v[1] * aq.y + v[2] * aq.z + v[3] * aq.w;
    }
#pragma unroll
    for (int ct = 0; ct < 4; ++ct) {
        float4 aq = ((const float4*)a1v)[ct * 4 + lk];
        f32x4 v = acc[4 + ct];
        p1 += v[0] * aq.x + v[1] * aq.y + v[2] * aq.z + v[3] * aq.w;
    }
    p0 += __shfl_xor(p0, 16); p0 += __shfl_xor(p0, 32);
    p1 += __shfl_xor(p1, 16); p1 += __shfl_xor(p1, 32);
    if (row < N) {
#pragma unroll
        for (int ct = 0; ct < 4; ++ct) {
            f32x4 v = acc[ct];
            __half2 h01 = __floats2half2_rn(v[0], v[1]);
            __half2 h23 = __floats2half2_rn(v[2], v[3]);
            uint2 pk;
            pk.x = *(const unsigned int*)&h01;
            pk.y = *(const unsigned int*)&h23;
            *(uint2*)(out0 + ((size_t)row << 6) + ct * 16 + lk * 4) = pk;
        }
        if (lane < 16) { al0[row] = p0; al1[row] = p1; }
    }
}

// ========== GAT aggregation v9: 16-lane group/dst; OUT_MODE 1 = half rows (layer 1),
// OUT_MODE 2 = fused decoder projection: write pm[d] = out_row @ Wc_slice (float2).
// zm2/zc2 rows never hit memory in mode 2 — decoder gathers shrink 128B -> 8B. ==========
#define AGG_CAP 64
#define AGG_PAD 66

template <int RELU, int OUT_MODE>
__global__ __launch_bounds__(256) void gat_aggregate9(
    const int* __restrict__ off0, const int* __restrict__ csr0,
    const __half* __restrict__ hs0, const float* __restrict__ als0,
    const float* __restrict__ ald0, const float* __restrict__ bias0,
    void* __restrict__ outp0, const float* __restrict__ wc0, int n0,
    const int* __restrict__ off1, const int* __restrict__ csr1,
    const __half* __restrict__ hs1, const float* __restrict__ als1,
    const float* __restrict__ ald1, const float* __restrict__ bias1,
    void* __restrict__ outp1, const float* __restrict__ wc1, int n1,
    int nb0) {
    __shared__ uint2 wP[16][AGG_PAD];
    int t = threadIdx.x;
    int slot = t >> 4;
    int sub = t & 15;

    const int* off; const int* csr; const __half* hs; const float* als;
    const float* ald; const float* bias; void* outp; const float* wc; int nd; int b;
    if (blockIdx.x < (unsigned)nb0) {
        b = blockIdx.x;
        off = off0; csr = csr0; hs = hs0; als = als0; ald = ald0; bias = bias0;
        outp = outp0; wc = wc0; nd = n0;
    } else {
        b = blockIdx.x - nb0;
        off = off1; csr = csr1; hs = hs1; als = als1; ald = ald1; bias = bias1;
        outp = outp1; wc = wc1; nd = n1;
    }
    int d = b * 16 + slot;
    bool active = d < nd;
    int beg = 0, deg = 0;
    float aldv = 0.f;
    if (active) {
        beg = off[d];
        deg = off[d + 1] - beg;
        aldv = ald[d];
    }
    float4 bl4 = ((const float4*)bias)[sub];
    uint2* WP = wP[slot];

    // pass 1: weights + denom (16-lane stripe)
    float sum = 0.f;
    for (int i = sub; i < deg; i += 16) {
        int s = csr[beg + i];
        float a = als[s] + aldv;
        a = (a >= 0.f) ? a : 0.2f * a;
        float w = exp_am8(a);
        sum += w;
        if (i < AGG_CAP) {
            __half hw = __float2half_rn(w);
            __half2 h2 = __half2half2(hw);
            WP[i] = make_uint2(*(const unsigned int*)&h2, (unsigned int)s);
        }
    }
    sum += __shfl_xor(sum, 1);
    sum += __shfl_xor(sum, 2);
    sum += __shfl_xor(sum, 4);
    sum += __shfl_xor(sum, 8);
    float inv = 1.f / fmaxf(sum, 1e-16f);

    // pass 2: 4 channels/lane; 8-deep then 2-step then remainder
    int dc = deg < AGG_CAP ? deg : AGG_CAP;
    const uint2* hs4 = (const uint2*)hs;   // row = 16 x uint2 (64 ch)
    __half2 z = __floats2half2_rn(0.f, 0.f);
    __half2 aA = z, aB = z, aC = z, aD = z;
    int i = 0;
    for (; i + 8 <= dc; i += 8) {
        uint4 q0 = *(const uint4*)&WP[i];
        uint4 q1 = *(const uint4*)&WP[i + 2];
        uint4 q2 = *(const uint4*)&WP[i + 4];
        uint4 q3 = *(const uint4*)&WP[i + 6];
        uint2 v0 = hs4[(size_t)q0.y * 16 + sub];
        uint2 v1 = hs4[(size_t)q0.w * 16 + sub];
        uint2 v2 = hs4[(size_t)q1.y * 16 + sub];
        uint2 v3 = hs4[(size_t)q1.w * 16 + sub];
        uint2 v4 = hs4[(size_t)q2.y * 16 + sub];
        uint2 v5 = hs4[(size_t)q2.w * 16 + sub];
        uint2 v6 = hs4[(size_t)q3.y * 16 + sub];
        uint2 v7 = hs4[(size_t)q3.w * 16 + sub];
        aA = __hfma2(*(const __half2*)&q0.x, *(const __half2*)&v0.x, aA);
        aB = __hfma2(*(const __half2*)&q0.x, *(const __half2*)&v0.y, aB);
        aC = __hfma2(*(const __half2*)&q0.z, *(const __half2*)&v1.x, aC);
        aD = __hfma2(*(const __half2*)&q0.z, *(const __half2*)&v1.y, aD);
        aA = __hfma2(*(const __half2*)&q1.x, *(const __half2*)&v2.x, aA);
        aB = __hfma2(*(const __half2*)&q1.x, *(const __half2*)&v2.y, aB);
        aC = __hfma2(*(const __half2*)&q1.z, *(const __half2*)&v3.x, aC);
        aD = __hfma2(*(const __half2*)&q1.z, *(const __half2*)&v3.y, aD);
        aA = __hfma2(*(const __half2*)&q2.x, *(const __half2*)&v4.x, aA);
        aB = __hfma2(*(const __half2*)&q2.x, *(const __half2*)&v4.y, aB);
        aC = __hfma2(*(const __half2*)&q2.z, *(const __half2*)&v5.x, aC);
        aD = __hfma2(*(const __half2*)&q2.z, *(const __half2*)&v5.y, aD);
        aA = __hfma2(*(const __half2*)&q3.x, *(const __half2*)&v6.x, aA);
        aB = __hfma2(*(const __half2*)&q3.x, *(const __half2*)&v6.y, aB);
        aC = __hfma2(*(const __half2*)&q3.z, *(const __half2*)&v7.x, aC);
        aD = __hfma2(*(const __half2*)&q3.z, *(const __half2*)&v7.y, aD);
    }
    for (; i + 2 <= dc; i += 2) {
        uint4 q = *(const uint4*)&WP[i];
        uint2 v0 = hs4[(size_t)q.y * 16 + sub];
        uint2 v1 = hs4[(size_t)q.w * 16 + sub];
        aA = __hfma2(*(const __half2*)&q.x, *(const __half2*)&v0.x, aA);
        aB = __hfma2(*(const __half2*)&q.x, *(const __half2*)&v0.y, aB);
        aC = __hfma2(*(const __half2*)&q.z, *(const __half2*)&v1.x, aC);
        aD = __hfma2(*(const __half2*)&q.z, *(const __half2*)&v1.y, aD);
    }
    if (i < dc) {
        uint2 u = WP[i];
        uint2 v = hs4[(size_t)u.y * 16 + sub];
        aA = __hfma2(*(const __half2*)&u.x, *(const __half2*)&v.x, aA);
        aB = __hfma2(*(const __half2*)&u.x, *(const __half2*)&v.y, aB);
    }
    // exact fallback for deg > AGG_CAP (recompute weight)
    for (int j = AGG_CAP; j < deg; ++j) {
        int s = csr[beg + j];
        float a = als[s] + aldv;
        a = (a >= 0.f) ? a : 0.2f * a;
        __half hw = __float2half_rn(exp_am8(a));
        __half2 w2 = __half2half2(hw);
        uint2 v = hs4[(size_t)s * 16 + sub];
        aA = __hfma2(w2, *(const __half2*)&v.x, aA);
        aB = __hfma2(w2, *(const __half2*)&v.y, aB);
    }
    float2 fA = __half22float2(aA);
    float2 fB = __half22float2(aB);
    float2 fC = __half22float2(aC);
    float2 fD = __half22float2(aD);
    float o0 = (fA.x + fC.x) * inv + bl4.x;
    float o1 = (fA.y + fC.y) * inv + bl4.y;
    float o2 = (fB.x + fD.x) * inv + bl4.z;
    float o3 = (fB.y + fD.y) * inv + bl4.w;
    if (deg == 0) { o0 = bl4.x; o1 = bl4.y; o2 = bl4.z; o3 = bl4.w; }
    if (RELU) {
        o0 = fmaxf(o0, 0.f); o1 = fmaxf(o1, 0.f);
        o2 = fmaxf(o2, 0.f); o3 = fmaxf(o3, 0.f);
    }
    if (OUT_MODE == 1) {
        if (active) {
            __half2 h01 = __floats2half2_rn(o0, o1);
            __half2 h23 = __floats2half2_rn(o2, o3);
            uint2 pk;
            pk.x = *(const unsigned int*)&h01;
            pk.y = *(const unsigned int*)&h23;
            ((uint2*)outp)[(size_t)d * 16 + sub] = pk;
        }
    } else {
        // fused decoder projection: pm[d] = sum_ch out[ch] * wc[ch][0..1]
        const float2* wcp = (const float2*)wc;
        float2 w0 = wcp[sub * 4 + 0];
        float2 w1 = wcp[sub * 4 + 1];
        float2 w2 = wcp[sub * 4 + 2];
        float2 w3 = wcp[sub * 4 + 3];
        float p0 = o0 * w0.x + o1 * w1.x + o2 * w2.x + o3 * w3.x;
        float p1 = o0 * w0.y + o1 * w1.y + o2 * w2.y + o3 * w3.y;
        p0 += __shfl_xor(p0, 1); p1 += __shfl_xor(p1, 1);
        p0 += __shfl_xor(p0, 2); p1 += __shfl_xor(p1, 2);
        p0 += __shfl_xor(p0, 4); p1 += __shfl_xor(p1, 4);
        p0 += __shfl_xor(p0, 8); p1 += __shfl_xor(p1, 8);
        if (active && sub == 0)
            ((float2*)outp)[d] = make_float2(p0, p1);
    }
}

// ---------------- decoder v4: out[e] = pm[row] + pc[col] + bc (8B L2-resident gathers) ----
__global__ __launch_bounds__(256) void decoder4_kernel(const int* __restrict__ row,
                                                       const int* __restrict__ col,
                                                       const float2* __restrict__ pm,
                                                       const float2* __restrict__ pc,
                                                       const float* __restrict__ bc,
                                                       float* __restrict__ out, int EL) {
    int e = blockIdx.x * 256 + threadIdx.x;
    if (e >= EL) return;
    float2 a = pm[row[e]];
    float2 b = pc[col[e]];
    *(float2*)(out + 2 * (size_t)e) = make_float2(a.x + b.x + bc[0], a.y + b.y + bc[1]);
}

// ---------------- launch ----------------
extern "C" void kernel_launch(void* const* d_in, const int* in_sizes, int n_in,
                              void* d_out, int out_size, void* d_ws, size_t ws_size,
                              hipStream_t stream) {
    const int D = 128;
    const float* x_m    = (const float*)d_in[0];
    const float* x_c    = (const float*)d_in[1];
    const int*   src_mc = (const int*)d_in[2];
    const int*   dst_mc = (const int*)d_in[3];
    const int*   src_cm = (const int*)d_in[4];
    const int*   dst_cm = (const int*)d_in[5];
    const int*   rowi   = (const int*)d_in[6];
    const int*   coli   = (const int*)d_in[7];
    const float* W1s_mc = (const float*)d_in[8];
    const float* W1d_mc = (const float*)d_in[9];
    const float* a1s_mc = (const float*)d_in[10];
    const float* a1d_mc = (const float*)d_in[11];
    const float* b1_mc  = (const float*)d_in[12];
    const float* W1s_cm = (const float*)d_in[13];
    const float* W1d_cm = (const float*)d_in[14];
    const float* a1s_cm = (const float*)d_in[15];
    const float* a1d_cm = (const float*)d_in[16];
    const float* b1_cm  = (const float*)d_in[17];
    const float* W2s_mc = (const float*)d_in[18];
    const float* W2d_mc = (const float*)d_in[19];
    const float* a2s_mc = (const float*)d_in[20];
    const float* a2d_mc = (const float*)d_in[21];
    const float* b2_mc  = (const float*)d_in[22];
    const float* W2s_cm = (const float*)d_in[23];
    const float* W2d_cm = (const float*)d_in[24];
    const float* a2s_cm = (const float*)d_in[25];
    const float* a2d_cm = (const float*)d_in[26];
    const float* b2_cm  = (const float*)d_in[27];
    const float* Wd1    = (const float*)d_in[28];
    const float* bd1    = (const float*)d_in[29];
    const float* Wd2    = (const float*)d_in[30];
    const float* bd2    = (const float*)d_in[31];

    const int N_M = in_sizes[0] / D;
    const int N_C = in_sizes[1] / D;
    const int E   = in_sizes[2];
    const int EL  = in_sizes[6];
    float* out = (float*)d_out;

    uint8_t* base = (uint8_t*)d_ws;
    size_t off = 0;
    auto carve = [&](size_t bytes) -> void* {
        void* p = base + off;
        off += (bytes + 255) & ~(size_t)255;
        return p;
    };
    __half* hsA_h = (__half*)carve((size_t)N_M * 64 * 2);
    __half* hsB_h = (__half*)carve((size_t)N_C * 64 * 2);
    __half* zm1_h = (__half*)carve((size_t)N_M * 64 * 2);
    __half* zc1_h = (__half*)carve((size_t)N_C * 64 * 2);
    float2* pm_m  = (float2*)carve((size_t)N_M * 8);   // fused decoder proj (materials)
    float2* pm_c  = (float2*)carve((size_t)N_C * 8);   // fused decoder proj (concepts)
    float* als_mc = (float*)carve((size_t)N_M * 4);
    float* ald_cm = (float*)carve((size_t)N_M * 4);
    float* als_cm = (float*)carve((size_t)N_C * 4);
    float* ald_mc = (float*)carve((size_t)N_C * 4);
    int* off_mc = (int*)carve((size_t)(N_C + 1) * 4);
    int* off_cm = (int*)carve((size_t)(N_M + 1) * 4);
    int* csr_mc = (int*)carve((size_t)E * 4);
    int* csr_cm = (int*)carve((size_t)E * 4);
    unsigned* pairs_mc = (unsigned*)carve((size_t)E * 4);
    unsigned* pairs_cm = (unsigned*)carve((size_t)E * 4);
    int* bcnt_base = (int*)carve(512 * 4);
    int* bcnt_mc = bcnt_base;
    int* bcnt_cm = bcnt_base + 256;
    int* bbase_mc = (int*)carve(257 * 4);
    int* bbase_cm = (int*)carve(257 * 4);
    int* bcur_mc = (int*)carve(256 * 4);
    int* bcur_cm = (int*)carve(256 * 4);
    _Float16* wp1A = (_Float16*)carve(128 * 128 * 2);
    _Float16* wp1B = (_Float16*)carve(128 * 128 * 2);
    _Float16* wp2A = (_Float16*)carve(128 * 64 * 2);
    _Float16* wp2B = (_Float16*)carve(128 * 64 * 2);
    float* Wc = (float*)carve(256 * 4);
    float* bc = (float*)carve(256);

    int shA = 0; while (((N_C + (1 << shA) - 1) >> shA) > 256) shA++;
    int shB = 0; while (((N_M + (1 << shB) - 1) >> shB) > 256) shB++;
    int nbkA = (N_C + (1 << shA) - 1) >> shA;
    int nbkB = (N_M + (1 << shB) - 1) >> shB;
    int maxN = N_M > N_C ? N_M : N_C;
    int srcbits = 1; while ((1 << srcbits) < maxN) srcbits++;

    // ---- W fragment pre-pack + decoder Wc prep ----
    pack_w_all<<<192, 256, 0, stream>>>(W1s_mc, W1d_cm, wp1A,
                                        W1s_cm, W1d_mc, wp1B,
                                        W2s_mc, W2d_cm, wp2A,
                                        W2s_cm, W2d_mc, wp2B);
    decoder_prep<<<1, 256, 0, stream>>>(Wd1, bd1, Wd2, bd2, Wc, bc);

    // ---- CSR build (bucket-first) ----
    hipMemsetAsync(bcnt_base, 0, 512 * 4, stream);
    int nblk = (E + 4095) / 4096;
    bucket_hist<<<2 * nblk, 256, 0, stream>>>(dst_mc, bcnt_mc, shA,
                                              dst_cm, bcnt_cm, shB, E, nblk);
    bucket_scan<<<1, 128, 0, stream>>>(bcnt_mc, nbkA, bbase_mc, bcur_mc, off_mc, N_C,
                                       bcnt_cm, nbkB, bbase_cm, bcur_cm, off_cm, N_M, E);
    bucket_scatter<<<2 * nblk, 256, 0, stream>>>(
        src_mc, dst_mc, bcur_mc, pairs_mc,
        src_cm, dst_cm, bcur_cm, pairs_cm, E, nblk, shA, shB, srcbits);
    bucket_expand2<<<nbkA + nbkB, 256, 0, stream>>>(
        pairs_mc, bbase_mc, N_C, off_mc, csr_mc, shA, nbkA,
        pairs_cm, bbase_cm, N_M, off_cm, csr_cm, shB, srcbits);

    int nb_c = (N_C + 15) / 16;
    int nb_m = (N_M + 15) / 16;

    // ---- Layer 1 (f32 inputs -> fp16 MFMA; aggregates write fp16 rows) ----
    proj_mfma3_kernel<128, float><<<(N_M + 63) / 64, 256, 0, stream>>>(
        x_m, N_M, wp1A, a1s_mc, a1d_cm, hsA_h, als_mc, ald_cm);
    proj_mfma3_kernel<128, float><<<(N_C + 63) / 64, 256, 0, stream>>>(
        x_c, N_C, wp1B, a1s_cm, a1d_mc, hsB_h, als_cm, ald_mc);
    gat_aggregate9<1, 1><<<nb_c + nb_m, 256, 0, stream>>>(
        off_mc, csr_mc, hsA_h, als_mc, ald_mc, b1_mc, zc1_h, nullptr, N_C,
        off_cm, csr_cm, hsB_h, als_cm, ald_cm, b1_cm, zm1_h, nullptr, N_M, nb_c);

    // ---- Layer 2 (fp16 inputs; aggregates fuse the decoder projection -> pm/pc) ----
    proj_mfma3_kernel<64, __half><<<(N_M + 63) / 64, 256, 0, stream>>>(
        zm1_h, N_M, wp2A, a2s_mc, a2d_cm, hsA_h, als_mc, ald_cm);
    proj_mfma3_kernel<64, __half><<<(N_C + 63) / 64, 256, 0, stream>>>(
        zc1_h, N_C, wp2B, a2s_cm, a2d_mc, hsB_h, als_cm, ald_mc);
    // graph0 dsts = concepts -> pc, Wc rows 64..127; graph1 dsts = materials -> pm, rows 0..63
    gat_aggregate9<0, 2><<<nb_c + nb_m, 256, 0, stream>>>(
        off_mc, csr_mc, hsA_h, als_mc, ald_mc, b2_mc, pm_c, Wc + 128, N_C,
        off_cm, csr_cm, hsB_h, als_cm, ald_cm, b2_cm, pm_m, Wc, N_M, nb_c);

    // ---- Decoder: out[e] = pm[row] + pc[col] + bc ----
    decoder4_kernel<<<(EL + 255) / 256, 256, 0, stream>>>(rowi, coli, pm_m, pm_c, bc, out, EL);
}

// Round 20
// 227.282 us; speedup vs baseline: 1.2746x; 1.1509x over previous
//
#include <hip/hip_runtime.h>
#include <hip/hip_fp16.h>
#include <cstdint>
#include <cstddef>

typedef _Float16 f16x8 __attribute__((ext_vector_type(8)));
typedef float f32x4 __attribute__((ext_vector_type(4)));

__device__ __forceinline__ float exp_am8(float a) {
    // exp(a-8) == 2^(a*log2e - 8*log2e); single v_exp_f32
    return __builtin_amdgcn_exp2f(fmaf(a, 1.442695040888963f, -11.541560327111707f));
}

// ================= CSR build: bucket-first, no per-dst global histogram =================
__global__ __launch_bounds__(256) void bucket_hist(const int* __restrict__ dA,
                                                   int* __restrict__ bcntA, int shA,
                                                   const int* __restrict__ dB,
                                                   int* __restrict__ bcntB, int shB,
                                                   int E, int nblkA) {
    __shared__ int h[256];
    const int* dst; int* bcnt; int sh; int base;
    if ((int)blockIdx.x < nblkA) { dst = dA; bcnt = bcntA; sh = shA; base = blockIdx.x * 4096; }
    else { dst = dB; bcnt = bcntB; sh = shB; base = (blockIdx.x - nblkA) * 4096; }
    int t = threadIdx.x;
    h[t] = 0;
    __syncthreads();
#pragma unroll
    for (int j = 0; j < 16; ++j) {
        int i = base + j * 256 + t;
        if (i < E) atomicAdd(&h[dst[i] >> sh], 1);
    }
    __syncthreads();
    int c = h[t];
    if (c > 0) atomicAdd(&bcnt[t], c);
}

__global__ void bucket_scan(const int* __restrict__ bcntA, int nbkA,
                            int* __restrict__ bbaseA, int* __restrict__ bcurA,
                            int* __restrict__ offA, int nA,
                            const int* __restrict__ bcntB, int nbkB,
                            int* __restrict__ bbaseB, int* __restrict__ bcurB,
                            int* __restrict__ offB, int nB, int E) {
    int t = threadIdx.x;
    if (t == 0) {
        int run = 0;
        for (int i = 0; i < nbkA; ++i) { bbaseA[i] = run; bcurA[i] = run; run += bcntA[i]; }
        bbaseA[nbkA] = run;
        offA[nA] = E;
    }
    if (t == 64) {
        int run = 0;
        for (int i = 0; i < nbkB; ++i) { bbaseB[i] = run; bcurB[i] = run; run += bcntB[i]; }
        bbaseB[nbkB] = run;
        offB[nB] = E;
    }
}

__global__ __launch_bounds__(256) void bucket_scatter(
    const int* __restrict__ srcA, const int* __restrict__ dstA,
    int* __restrict__ bcurA, unsigned* __restrict__ pairsA,
    const int* __restrict__ srcB, const int* __restrict__ dstB,
    int* __restrict__ bcurB, unsigned* __restrict__ pairsB,
    int E, int nblkA, int shA, int shB, int srcbits) {
    __shared__ int bcnt[256];
    __shared__ int bbase[256];
    const int* src; const int* dst; int* bcur; unsigned* pairs; int sh; int base;
    if ((int)blockIdx.x < nblkA) {
        src = srcA; dst = dstA; bcur = bcurA; pairs = pairsA; sh = shA;
        base = blockIdx.x * 4096;
    } else {
        src = srcB; dst = dstB; bcur = bcurB; pairs = pairsB; sh = shB;
        base = (blockIdx.x - nblkA) * 4096;
    }
    int t = threadIdx.x;
    int msk = (1 << sh) - 1;
    bcnt[t] = 0;
    __syncthreads();
    int sreg[16], dreg[16];
#pragma unroll
    for (int j = 0; j < 16; ++j) {
        int i = base + j * 256 + t;
        if (i < E) {
            sreg[j] = src[i];
            dreg[j] = dst[i];
            atomicAdd(&bcnt[dreg[j] >> sh], 1);
        } else {
            dreg[j] = -1;
        }
    }
    __syncthreads();
    {
        int c = bcnt[t];
        int g = (c > 0) ? atomicAdd(&bcur[t], c) : 0;
        bbase[t] = g;
        bcnt[t] = 0;
    }
    __syncthreads();
#pragma unroll
    for (int j = 0; j < 16; ++j) {
        if (dreg[j] >= 0) {
            int b = dreg[j] >> sh;
            int r = atomicAdd(&bcnt[b], 1);
            pairs[bbase[b] + r] = ((unsigned)(dreg[j] & msk) << srcbits) | (unsigned)sreg[j];
        }
    }
}

__global__ __launch_bounds__(256) void bucket_expand2(
    const unsigned* __restrict__ pairsA, const int* __restrict__ bbaseA, int nA,
    int* __restrict__ offA, int* __restrict__ csrA, int shA, int nbA,
    const unsigned* __restrict__ pairsB, const int* __restrict__ bbaseB, int nB,
    int* __restrict__ offB, int* __restrict__ csrB, int shB, int srcbits) {
    __shared__ int lcnt[1024];
    __shared__ int red[256];
    const unsigned* pairs; const int* bbase; int n; int* off; int* csr; int sh; int b;
    if ((int)blockIdx.x < nbA) {
        pairs = pairsA; bbase = bbaseA; n = nA; off = offA; csr = csrA; sh = shA;
        b = blockIdx.x;
    } else {
        pairs = pairsB; bbase = bbaseB; n = nB; off = offB; csr = csrB; sh = shB;
        b = blockIdx.x - nbA;
    }
    int dpb = 1 << sh;
    int d0 = b << sh;
    int t = threadIdx.x;
    unsigned smask = (1u << srcbits) - 1u;
    for (int dl = t; dl < dpb; dl += 256) lcnt[dl] = 0;
    __syncthreads();
    int pbeg = bbase[b], pend = bbase[b + 1];
    for (int i = pbeg + t; i < pend; i += 256)
        atomicAdd(&lcnt[pairs[i] >> srcbits], 1);
    __syncthreads();
    int per = (dpb + 255) >> 8;
    int i0 = t * per;
    int s = 0;
    for (int j = 0; j < per; ++j) {
        int dl = i0 + j;
        if (dl < dpb) s += lcnt[dl];
    }
    red[t] = s;
    __syncthreads();
    for (int st = 1; st < 256; st <<= 1) {
        int tmp = (t >= st) ? red[t - st] : 0;
        __syncthreads();
        red[t] += tmp;
        __syncthreads();
    }
    int run = pbeg + red[t] - s;
    for (int j = 0; j < per; ++j) {
        int dl = i0 + j;
        if (dl < dpb) {
            int c = lcnt[dl];
            if (d0 + dl < n) off[d0 + dl] = run;
            lcnt[dl] = run;
            run += c;
        }
    }
    __syncthreads();
    for (int i = pbeg + t; i < pend; i += 256) {
        unsigned p = pairs[i];
        int dl = (int)(p >> srcbits);
        int pos = atomicAdd(&lcnt[dl], 1);
        csr[pos] = (int)(p & smask);
    }
}

// ========== fragment-ordered W pack — all 4 matrices in ONE launch ==========
__global__ __launch_bounds__(256) void pack_w_all(
    const float* __restrict__ Wa0, const float* __restrict__ Wb0, _Float16* __restrict__ P0,
    const float* __restrict__ Wa1, const float* __restrict__ Wb1, _Float16* __restrict__ P1,
    const float* __restrict__ Wa2, const float* __restrict__ Wb2, _Float16* __restrict__ P2,
    const float* __restrict__ Wa3, const float* __restrict__ Wb3, _Float16* __restrict__ P3) {
    int b = blockIdx.x;
    const float* Wa; const float* Wb; _Float16* Wp; int K; int lb;
    if (b < 64)       { Wa = Wa0; Wb = Wb0; Wp = P0; K = 128; lb = b; }
    else if (b < 128) { Wa = Wa1; Wb = Wb1; Wp = P1; K = 128; lb = b - 64; }
    else if (b < 160) { Wa = Wa2; Wb = Wb2; Wp = P2; K = 64;  lb = b - 128; }
    else              { Wa = Wa3; Wb = Wb3; Wp = P3; K = 64;  lb = b - 160; }
    int NKB = K / 32;
    int i = lb * 256 + threadIdx.x;
    if (i >= 128 * K) return;
    int k = i >> 7, c = i & 127;
    float v = (c < 64) ? Wa[k * 64 + c] : Wb[k * 64 + (c - 64)];
    int ct = c >> 4, lr = c & 15, kb = k >> 5, lk = (k & 31) >> 3, e = k & 7;
    Wp[((ct * NKB + kb) * 64 + (lr + 16 * lk)) * 8 + e] = (_Float16)v;
}

// ---- decoder prep2: Wc = Wd1@Wd2 [128,2]; bc = bd1@Wd2 + bd2; bq_m = b2_cm@Wc[0:64],
// bq_c = b2_mc@Wc[64:128]  (constants folded into pm/pc) ----
__global__ void decoder_prep2(const float* __restrict__ Wd1, const float* __restrict__ bd1,
                              const float* __restrict__ Wd2, const float* __restrict__ bd2,
                              const float* __restrict__ b2_cm, const float* __restrict__ b2_mc,
                              float* __restrict__ Wc, float* __restrict__ bc,
                              float* __restrict__ bq) {
    __shared__ float WcS[256];
    int t = threadIdx.x;
    int k = t >> 1, c = t & 1;
    float s = 0.f;
    for (int j = 0; j < 64; ++j) s += Wd1[k * 64 + j] * Wd2[j * 2 + c];
    Wc[k * 2 + c] = s;
    WcS[k * 2 + c] = s;
    if (k == 0) {
        float b = bd2[c];
        for (int j = 0; j < 64; ++j) b += bd1[j] * Wd2[j * 2 + c];
        bc[c] = b;
    }
    __syncthreads();
    if (t < 2) {            // bq_m[t] = sum_j b2_cm[j] * Wc[j][t]
        float v = 0.f;
        for (int j = 0; j < 64; ++j) v += b2_cm[j] * WcS[j * 2 + t];
        bq[t] = v;
    } else if (t < 4) {     // bq_c[t-2] = sum_j b2_mc[j] * Wc[64+j][t-2]
        int cc = t - 2;
        float v = 0.f;
        for (int j = 0; j < 64; ++j) v += b2_mc[j] * WcS[(64 + j) * 2 + cc];
        bq[t] = v;
    }
}

// ================= MFMA dual projection: zero-conflict LDS, X direct-to-reg =============
// QMODE 0: store X@Wa rows as fp16 (table for layer-1 gathers) + logits.
// QMODE 1: store ONLY q[row] = (X@Wa)@wcq (float2) + logits — layer-2 rows never hit memory.
template <int K, typename TIN, int QMODE>
__global__ __launch_bounds__(256) void proj_mfma4_kernel(const TIN* __restrict__ X, int N,
                                                         const _Float16* __restrict__ Wp,
                                                         const float* __restrict__ a0v,
                                                         const float* __restrict__ a1v,
                                                         __half* __restrict__ out0,
                                                         const float* __restrict__ wcq,
                                                         float2* __restrict__ qtab,
                                                         float* __restrict__ al0,
                                                         float* __restrict__ al1) {
    constexpr int NKB = K / 32;
    __shared__ __align__(16) _Float16 Wlds[128 * K];
    int t = threadIdx.x;
    constexpr int NV = (128 * K) / 8;
#pragma unroll
    for (int i = t; i < NV; i += 256)
        ((uint4*)Wlds)[i] = ((const uint4*)Wp)[i];
    __syncthreads();

    int rt = blockIdx.x * 64;
    int wv = t >> 6, lane = t & 63, lr = lane & 15, lk = lane >> 4;
    int row = rt + wv * 16 + lr;
    int rowc = row < N ? row : N - 1;

    f32x4 acc[8];
#pragma unroll
    for (int i = 0; i < 8; ++i) acc[i] = f32x4{0.f, 0.f, 0.f, 0.f};

    const f16x8* Wf = (const f16x8*)Wlds;
#pragma unroll
    for (int kb = 0; kb < NKB; ++kb) {
        f16x8 bf;
        if constexpr (sizeof(TIN) == 4) {
            const float* xr = (const float*)X + (size_t)rowc * K + kb * 32 + lk * 8;
            float4 x0 = *(const float4*)xr;
            float4 x1 = *(const float4*)(xr + 4);
            bf[0] = (_Float16)x0.x; bf[1] = (_Float16)x0.y;
            bf[2] = (_Float16)x0.z; bf[3] = (_Float16)x0.w;
            bf[4] = (_Float16)x1.x; bf[5] = (_Float16)x1.y;
            bf[6] = (_Float16)x1.z; bf[7] = (_Float16)x1.w;
        } else {
            bf = *(const f16x8*)((const _Float16*)X + (size_t)rowc * K + kb * 32 + lk * 8);
        }
#pragma unroll
        for (int ct = 0; ct < 8; ++ct) {
            acc[ct] = __builtin_amdgcn_mfma_f32_16x16x32_f16(Wf[(ct * NKB + kb) * 64 + lane],
                                                             bf, acc[ct], 0, 0, 0);
        }
    }

    float p0 = 0.f, p1 = 0.f;
#pragma unroll
    for (int ct = 0; ct < 4; ++ct) {
        float4 aq = ((const float4*)a0v)[ct * 4 + lk];
        f32x4 v = acc[ct];
        p0 += v[0] * aq.x + v[1] * aq.y + v[2] * aq.z + v[3] * aq.w;
    }
#pragma unroll
    for (int ct = 0; ct < 4; ++ct) {
        float4 aq = ((const float4*)a1v)[ct * 4 + lk];
        f32x4 v = acc[4 + ct];
        p1 += v[0] * aq.x + v[1] * aq.y + v[2] * aq.z + v[3] * aq.w;
    }
    p0 += __shfl_xor(p0, 16); p0 += __shfl_xor(p0, 32);
    p1 += __shfl_xor(p1, 16); p1 += __shfl_xor(p1, 32);

    if (QMODE == 1) {
        // q[row] = sum_ch acc_ch * wcq[ch][0:2]; lane's channels: ct*16 + lk*4 + j
        float qx = 0.f, qy = 0.f;
#pragma unroll
        for (int ct = 0; ct < 4; ++ct) {
            f32x4 v = acc[ct];
#pragma unroll
            for (int j = 0; j < 4; ++j) {
                float2 w = ((const float2*)wcq)[ct * 16 + lk * 4 + j];
                qx = fmaf(v[j], w.x, qx);
                qy = fmaf(v[j], w.y, qy);
            }
        }
        qx += __shfl_xor(qx, 16); qx += __shfl_xor(qx, 32);
        qy += __shfl_xor(qy, 16); qy += __shfl_xor(qy, 32);
        if (row < N && lane < 16) {
            qtab[row] = make_float2(qx, qy);
            al0[row] = p0;
            al1[row] = p1;
        }
    } else {
        if (row < N) {
#pragma unroll
            for (int ct = 0; ct < 4; ++ct) {
                f32x4 v = acc[ct];
                __half2 h01 = __floats2half2_rn(v[0], v[1]);
                __half2 h23 = __floats2half2_rn(v[2], v[3]);
                uint2 pk;
                pk.x = *(const unsigned int*)&h01;
                pk.y = *(const unsigned int*)&h23;
                *(uint2*)(out0 + ((size_t)row << 6) + ct * 16 + lk * 4) = pk;
            }
            if (lane < 16) { al0[row] = p0; al1[row] = p1; }
        }
    }
}

// ========== GAT aggregation v9 (layer 1): 16-lane group/dst, fp16 row gathers ==========
#define AGG_CAP 64
#define AGG_PAD 66

template <int RELU>
__global__ __launch_bounds__(256) void gat_aggregate9(
    const int* __restrict__ off0, const int* __restrict__ csr0,
    const __half* __restrict__ hs0, const float* __restrict__ als0,
    const float* __restrict__ ald0, const float* __restrict__ bias0,
    void* __restrict__ outp0, int n0,
    const int* __restrict__ off1, const int* __restrict__ csr1,
    const __half* __restrict__ hs1, const float* __restrict__ als1,
    const float* __restrict__ ald1, const float* __restrict__ bias1,
    void* __restrict__ outp1, int n1,
    int nb0) {
    __shared__ uint2 wP[16][AGG_PAD];
    int t = threadIdx.x;
    int slot = t >> 4;
    int sub = t & 15;

    const int* off; const int* csr; const __half* hs; const float* als;
    const float* ald; const float* bias; void* outp; int nd; int b;
    if (blockIdx.x < (unsigned)nb0) {
        b = blockIdx.x;
        off = off0; csr = csr0; hs = hs0; als = als0; ald = ald0; bias = bias0;
        outp = outp0; nd = n0;
    } else {
        b = blockIdx.x - nb0;
        off = off1; csr = csr1; hs = hs1; als = als1; ald = ald1; bias = bias1;
        outp = outp1; nd = n1;
    }
    int d = b * 16 + slot;
    bool active = d < nd;
    int beg = 0, deg = 0;
    float aldv = 0.f;
    if (active) {
        beg = off[d];
        deg = off[d + 1] - beg;
        aldv = ald[d];
    }
    float4 bl4 = ((const float4*)bias)[sub];
    uint2* WP = wP[slot];

    float sum = 0.f;
    for (int i = sub; i < deg; i += 16) {
        int s = csr[beg + i];
        float a = als[s] + aldv;
        a = (a >= 0.f) ? a : 0.2f * a;
        float w = exp_am8(a);
        sum += w;
        if (i < AGG_CAP) {
            __half hw = __float2half_rn(w);
            __half2 h2 = __half2half2(hw);
            WP[i] = make_uint2(*(const unsigned int*)&h2, (unsigned int)s);
        }
    }
    sum += __shfl_xor(sum, 1);
    sum += __shfl_xor(sum, 2);
    sum += __shfl_xor(sum, 4);
    sum += __shfl_xor(sum, 8);
    float inv = 1.f / fmaxf(sum, 1e-16f);

    int dc = deg < AGG_CAP ? deg : AGG_CAP;
    const uint2* hs4 = (const uint2*)hs;
    __half2 z = __floats2half2_rn(0.f, 0.f);
    __half2 aA = z, aB = z, aC = z, aD = z;
    int i = 0;
    for (; i + 8 <= dc; i += 8) {
        uint4 q0 = *(const uint4*)&WP[i];
        uint4 q1 = *(const uint4*)&WP[i + 2];
        uint4 q2 = *(const uint4*)&WP[i + 4];
        uint4 q3 = *(const uint4*)&WP[i + 6];
        uint2 v0 = hs4[(size_t)q0.y * 16 + sub];
        uint2 v1 = hs4[(size_t)q0.w * 16 + sub];
        uint2 v2 = hs4[(size_t)q1.y * 16 + sub];
        uint2 v3 = hs4[(size_t)q1.w * 16 + sub];
        uint2 v4 = hs4[(size_t)q2.y * 16 + sub];
        uint2 v5 = hs4[(size_t)q2.w * 16 + sub];
        uint2 v6 = hs4[(size_t)q3.y * 16 + sub];
        uint2 v7 = hs4[(size_t)q3.w * 16 + sub];
        aA = __hfma2(*(const __half2*)&q0.x, *(const __half2*)&v0.x, aA);
        aB = __hfma2(*(const __half2*)&q0.x, *(const __half2*)&v0.y, aB);
        aC = __hfma2(*(const __half2*)&q0.z, *(const __half2*)&v1.x, aC);
        aD = __hfma2(*(const __half2*)&q0.z, *(const __half2*)&v1.y, aD);
        aA = __hfma2(*(const __half2*)&q1.x, *(const __half2*)&v2.x, aA);
        aB = __hfma2(*(const __half2*)&q1.x, *(const __half2*)&v2.y, aB);
        aC = __hfma2(*(const __half2*)&q1.z, *(const __half2*)&v3.x, aC);
        aD = __hfma2(*(const __half2*)&q1.z, *(const __half2*)&v3.y, aD);
        aA = __hfma2(*(const __half2*)&q2.x, *(const __half2*)&v4.x, aA);
        aB = __hfma2(*(const __half2*)&q2.x, *(const __half2*)&v4.y, aB);
        aC = __hfma2(*(const __half2*)&q2.z, *(const __half2*)&v5.x, aC);
        aD = __hfma2(*(const __half2*)&q2.z, *(const __half2*)&v5.y, aD);
        aA = __hfma2(*(const __half2*)&q3.x, *(const __half2*)&v6.x, aA);
        aB = __hfma2(*(const __half2*)&q3.x, *(const __half2*)&v6.y, aB);
        aC = __hfma2(*(const __half2*)&q3.z, *(const __half2*)&v7.x, aC);
        aD = __hfma2(*(const __half2*)&q3.z, *(const __half2*)&v7.y, aD);
    }
    for (; i + 2 <= dc; i += 2) {
        uint4 q = *(const uint4*)&WP[i];
        uint2 v0 = hs4[(size_t)q.y * 16 + sub];
        uint2 v1 = hs4[(size_t)q.w * 16 + sub];
        aA = __hfma2(*(const __half2*)&q.x, *(const __half2*)&v0.x, aA);
        aB = __hfma2(*(const __half2*)&q.x, *(const __half2*)&v0.y, aB);
        aC = __hfma2(*(const __half2*)&q.z, *(const __half2*)&v1.x, aC);
        aD = __hfma2(*(const __half2*)&q.z, *(const __half2*)&v1.y, aD);
    }
    if (i < dc) {
        uint2 u = WP[i];
        uint2 v = hs4[(size_t)u.y * 16 + sub];
        aA = __hfma2(*(const __half2*)&u.x, *(const __half2*)&v.x, aA);
        aB = __hfma2(*(const __half2*)&u.x, *(const __half2*)&v.y, aB);
    }
    for (int j = AGG_CAP; j < deg; ++j) {
        int s = csr[beg + j];
        float a = als[s] + aldv;
        a = (a >= 0.f) ? a : 0.2f * a;
        __half hw = __float2half_rn(exp_am8(a));
        __half2 w2 = __half2half2(hw);
        uint2 v = hs4[(size_t)s * 16 + sub];
        aA = __hfma2(w2, *(const __half2*)&v.x, aA);
        aB = __hfma2(w2, *(const __half2*)&v.y, aB);
    }
    float2 fA = __half22float2(aA);
    float2 fB = __half22float2(aB);
    float2 fC = __half22float2(aC);
    float2 fD = __half22float2(aD);
    float o0 = (fA.x + fC.x) * inv + bl4.x;
    float o1 = (fA.y + fC.y) * inv + bl4.y;
    float o2 = (fB.x + fD.x) * inv + bl4.z;
    float o3 = (fB.y + fD.y) * inv + bl4.w;
    if (deg == 0) { o0 = bl4.x; o1 = bl4.y; o2 = bl4.z; o3 = bl4.w; }
    if (RELU) {
        o0 = fmaxf(o0, 0.f); o1 = fmaxf(o1, 0.f);
        o2 = fmaxf(o2, 0.f); o3 = fmaxf(o3, 0.f);
    }
    if (active) {
        __half2 h01 = __floats2half2_rn(o0, o1);
        __half2 h23 = __floats2half2_rn(o2, o3);
        uint2 pk;
        pk.x = *(const unsigned int*)&h01;
        pk.y = *(const unsigned int*)&h23;
        ((uint2*)outp)[(size_t)d * 16 + sub] = pk;
    }
}

// ========== GAT aggregation v10 (layer 2): one dst per LANE, q-table gathers ==========
// pm[d] = (sum_e w_e * q[s_e]) / denom + bq   — q table 1.6MB/0.4MB, L2-resident; all f32.
__global__ __launch_bounds__(256) void gat_aggregate10(
    const int* __restrict__ off0, const int* __restrict__ csr0,
    const float2* __restrict__ q0, const float* __restrict__ als0,
    const float* __restrict__ ald0, const float2 bq0,
    float2* __restrict__ out0, int n0,
    const int* __restrict__ off1, const int* __restrict__ csr1,
    const float2* __restrict__ q1, const float* __restrict__ als1,
    const float* __restrict__ ald1, const float2 bq1,
    float2* __restrict__ out1, int n1,
    int nb0) {
    const int* off; const int* csr; const float2* qt; const float* als;
    const float* ald; float2 bq; float2* outp; int nd; int b;
    if (blockIdx.x < (unsigned)nb0) {
        b = blockIdx.x;
        off = off0; csr = csr0; qt = q0; als = als0; ald = ald0; bq = bq0;
        outp = out0; nd = n0;
    } else {
        b = blockIdx.x - nb0;
        off = off1; csr = csr1; qt = q1; als = als1; ald = ald1; bq = bq1;
        outp = out1; nd = n1;
    }
    int d = b * 256 + threadIdx.x;
    if (d >= nd) return;
    int beg = off[d], end = off[d + 1];
    float aldv = ald[d];
    float sum = 0.f, ax = 0.f, ay = 0.f;
    int i = beg;
    for (; i + 2 <= end; i += 2) {
        int s0 = csr[i], s1 = csr[i + 1];
        float a0 = als[s0] + aldv;
        float a1 = als[s1] + aldv;
        float2 v0 = qt[s0];
        float2 v1 = qt[s1];
        a0 = (a0 >= 0.f) ? a0 : 0.2f * a0;
        a1 = (a1 >= 0.f) ? a1 : 0.2f * a1;
        float w0 = exp_am8(a0);
        float w1 = exp_am8(a1);
        sum += w0 + w1;
        ax = fmaf(w0, v0.x, ax); ay = fmaf(w0, v0.y, ay);
        ax = fmaf(w1, v1.x, ax); ay = fmaf(w1, v1.y, ay);
    }
    if (i < end) {
        int s = csr[i];
        float a = als[s] + aldv;
        a = (a >= 0.f) ? a : 0.2f * a;
        float w = exp_am8(a);
        float2 v = qt[s];
        sum += w;
        ax = fmaf(w, v.x, ax); ay = fmaf(w, v.y, ay);
    }
    float inv = 1.f / fmaxf(sum, 1e-16f);
    outp[d] = make_float2(ax * inv + bq.x, ay * inv + bq.y);
}

// ---------------- decoder v4: out[e] = pm[row] + pc[col] + bc (8B L2-resident gathers) ----
__global__ __launch_bounds__(256) void decoder4_kernel(const int* __restrict__ row,
                                                       const int* __restrict__ col,
                                                       const float2* __restrict__ pm,
                                                       const float2* __restrict__ pc,
                                                       const float* __restrict__ bc,
                                                       float* __restrict__ out, int EL) {
    int e = blockIdx.x * 256 + threadIdx.x;
    if (e >= EL) return;
    float2 a = pm[row[e]];
    float2 b = pc[col[e]];
    *(float2*)(out + 2 * (size_t)e) = make_float2(a.x + b.x + bc[0], a.y + b.y + bc[1]);
}

// small helper: copy 4 floats (bq) to host-visible launch args via kernel arg is not possible;
// instead read bq on device inside aggregate10 via pointer — wrapped launch below uses a
// tiny kernel to splat bq into the two float2 args. Simpler: pass pointers.
__global__ void read_bq(const float* __restrict__ bq, float2* __restrict__ o) {
    if (threadIdx.x == 0) { o[0] = make_float2(bq[0], bq[1]); o[1] = make_float2(bq[2], bq[3]); }
}

// variant of aggregate10 taking bq via pointer (device-computed)
__global__ __launch_bounds__(256) void gat_aggregate10p(
    const int* __restrict__ off0, const int* __restrict__ csr0,
    const float2* __restrict__ q0, const float* __restrict__ als0,
    const float* __restrict__ ald0, const float2* __restrict__ bqp,
    float2* __restrict__ out0, int n0,
    const int* __restrict__ off1, const int* __restrict__ csr1,
    const float2* __restrict__ q1, const float* __restrict__ als1,
    const float* __restrict__ ald1,
    float2* __restrict__ out1, int n1,
    int nb0) {
    const int* off; const int* csr; const float2* qt; const float* als;
    const float* ald; float2 bq; float2* outp; int nd; int b;
    if (blockIdx.x < (unsigned)nb0) {
        b = blockIdx.x;
        off = off0; csr = csr0; qt = q0; als = als0; ald = ald0; bq = bqp[1];
        outp = out0; nd = n0;
    } else {
        b = blockIdx.x - nb0;
        off = off1; csr = csr1; qt = q1; als = als1; ald = ald1; bq = bqp[0];
        outp = out1; nd = n1;
    }
    int d = b * 256 + threadIdx.x;
    if (d >= nd) return;
    int beg = off[d], end = off[d + 1];
    float aldv = ald[d];
    float sum = 0.f, ax = 0.f, ay = 0.f;
    int i = beg;
    for (; i + 2 <= end; i += 2) {
        int s0 = csr[i], s1 = csr[i + 1];
        float a0 = als[s0] + aldv;
        float a1 = als[s1] + aldv;
        float2 v0 = qt[s0];
        float2 v1 = qt[s1];
        a0 = (a0 >= 0.f) ? a0 : 0.2f * a0;
        a1 = (a1 >= 0.f) ? a1 : 0.2f * a1;
        float w0 = exp_am8(a0);
        float w1 = exp_am8(a1);
        sum += w0 + w1;
        ax = fmaf(w0, v0.x, ax); ay = fmaf(w0, v0.y, ay);
        ax = fmaf(w1, v1.x, ax); ay = fmaf(w1, v1.y, ay);
    }
    if (i < end) {
        int s = csr[i];
        float a = als[s] + aldv;
        a = (a >= 0.f) ? a : 0.2f * a;
        float w = exp_am8(a);
        float2 v = qt[s];
        sum += w;
        ax = fmaf(w, v.x, ax); ay = fmaf(w, v.y, ay);
    }
    float inv = 1.f / fmaxf(sum, 1e-16f);
    outp[d] = make_float2(ax * inv + bq.x, ay * inv + bq.y);
}

// ---------------- launch ----------------
extern "C" void kernel_launch(void* const* d_in, const int* in_sizes, int n_in,
                              void* d_out, int out_size, void* d_ws, size_t ws_size,
                              hipStream_t stream) {
    const int D = 128;
    const float* x_m    = (const float*)d_in[0];
    const float* x_c    = (const float*)d_in[1];
    const int*   src_mc = (const int*)d_in[2];
    const int*   dst_mc = (const int*)d_in[3];
    const int*   src_cm = (const int*)d_in[4];
    const int*   dst_cm = (const int*)d_in[5];
    const int*   rowi   = (const int*)d_in[6];
    const int*   coli   = (const int*)d_in[7];
    const float* W1s_mc = (const float*)d_in[8];
    const float* W1d_mc = (const float*)d_in[9];
    const float* a1s_mc = (const float*)d_in[10];
    const float* a1d_mc = (const float*)d_in[11];
    const float* b1_mc  = (const float*)d_in[12];
    const float* W1s_cm = (const float*)d_in[13];
    const float* W1d_cm = (const float*)d_in[14];
    const float* a1s_cm = (const float*)d_in[15];
    const float* a1d_cm = (const float*)d_in[16];
    const float* b1_cm  = (const float*)d_in[17];
    const float* W2s_mc = (const float*)d_in[18];
    const float* W2d_mc = (const float*)d_in[19];
    const float* a2s_mc = (const float*)d_in[20];
    const float* a2d_mc = (const float*)d_in[21];
    const float* b2_mc  = (const float*)d_in[22];
    const float* W2s_cm = (const float*)d_in[23];
    const float* W2d_cm = (const float*)d_in[24];
    const float* a2s_cm = (const float*)d_in[25];
    const float* a2d_cm = (const float*)d_in[26];
    const float* b2_cm  = (const float*)d_in[27];
    const float* Wd1    = (const float*)d_in[28];
    const float* bd1    = (const float*)d_in[29];
    const float* Wd2    = (const float*)d_in[30];
    const float* bd2    = (const float*)d_in[31];

    const int N_M = in_sizes[0] / D;
    const int N_C = in_sizes[1] / D;
    const int E   = in_sizes[2];
    const int EL  = in_sizes[6];
    float* out = (float*)d_out;

    uint8_t* base = (uint8_t*)d_ws;
    size_t off = 0;
    auto carve = [&](size_t bytes) -> void* {
        void* p = base + off;
        off += (bytes + 255) & ~(size_t)255;
        return p;
    };
    __half* hsA_h = (__half*)carve((size_t)N_M * 64 * 2);
    __half* hsB_h = (__half*)carve((size_t)N_C * 64 * 2);
    __half* zm1_h = (__half*)carve((size_t)N_M * 64 * 2);
    __half* zc1_h = (__half*)carve((size_t)N_C * 64 * 2);
    float2* qA    = (float2*)carve((size_t)N_M * 8);   // layer-2 per-src decoder proj (mc)
    float2* qB    = (float2*)carve((size_t)N_C * 8);   // layer-2 per-src decoder proj (cm)
    float2* pm_m  = (float2*)carve((size_t)N_M * 8);
    float2* pm_c  = (float2*)carve((size_t)N_C * 8);
    float* als_mc = (float*)carve((size_t)N_M * 4);
    float* ald_cm = (float*)carve((size_t)N_M * 4);
    float* als_cm = (float*)carve((size_t)N_C * 4);
    float* ald_mc = (float*)carve((size_t)N_C * 4);
    int* off_mc = (int*)carve((size_t)(N_C + 1) * 4);
    int* off_cm = (int*)carve((size_t)(N_M + 1) * 4);
    int* csr_mc = (int*)carve((size_t)E * 4);
    int* csr_cm = (int*)carve((size_t)E * 4);
    unsigned* pairs_mc = (unsigned*)carve((size_t)E * 4);
    unsigned* pairs_cm = (unsigned*)carve((size_t)E * 4);
    int* bcnt_base = (int*)carve(512 * 4);
    int* bcnt_mc = bcnt_base;
    int* bcnt_cm = bcnt_base + 256;
    int* bbase_mc = (int*)carve(257 * 4);
    int* bbase_cm = (int*)carve(257 * 4);
    int* bcur_mc = (int*)carve(256 * 4);
    int* bcur_cm = (int*)carve(256 * 4);
    _Float16* wp1A = (_Float16*)carve(128 * 128 * 2);
    _Float16* wp1B = (_Float16*)carve(128 * 128 * 2);
    _Float16* wp2A = (_Float16*)carve(128 * 64 * 2);
    _Float16* wp2B = (_Float16*)carve(128 * 64 * 2);
    float* Wc = (float*)carve(256 * 4);
    float* bc = (float*)carve(256);
    float* bq = (float*)carve(256);          // [0:2]=bq_m, [2:4]=bq_c
    float2* bq2 = (float2*)bq;

    int shA = 0; while (((N_C + (1 << shA) - 1) >> shA) > 256) shA++;
    int shB = 0; while (((N_M + (1 << shB) - 1) >> shB) > 256) shB++;
    int nbkA = (N_C + (1 << shA) - 1) >> shA;
    int nbkB = (N_M + (1 << shB) - 1) >> shB;
    int maxN = N_M > N_C ? N_M : N_C;
    int srcbits = 1; while ((1 << srcbits) < maxN) srcbits++;

    // ---- W fragment pre-pack + decoder Wc/bq prep ----
    pack_w_all<<<192, 256, 0, stream>>>(W1s_mc, W1d_cm, wp1A,
                                        W1s_cm, W1d_mc, wp1B,
                                        W2s_mc, W2d_cm, wp2A,
                                        W2s_cm, W2d_mc, wp2B);
    decoder_prep2<<<1, 256, 0, stream>>>(Wd1, bd1, Wd2, bd2, b2_cm, b2_mc, Wc, bc, bq);

    // ---- CSR build (bucket-first) ----
    hipMemsetAsync(bcnt_base, 0, 512 * 4, stream);
    int nblk = (E + 4095) / 4096;
    bucket_hist<<<2 * nblk, 256, 0, stream>>>(dst_mc, bcnt_mc, shA,
                                              dst_cm, bcnt_cm, shB, E, nblk);
    bucket_scan<<<1, 128, 0, stream>>>(bcnt_mc, nbkA, bbase_mc, bcur_mc, off_mc, N_C,
                                       bcnt_cm, nbkB, bbase_cm, bcur_cm, off_cm, N_M, E);
    bucket_scatter<<<2 * nblk, 256, 0, stream>>>(
        src_mc, dst_mc, bcur_mc, pairs_mc,
        src_cm, dst_cm, bcur_cm, pairs_cm, E, nblk, shA, shB, srcbits);
    bucket_expand2<<<nbkA + nbkB, 256, 0, stream>>>(
        pairs_mc, bbase_mc, N_C, off_mc, csr_mc, shA, nbkA,
        pairs_cm, bbase_cm, N_M, off_cm, csr_cm, shB, srcbits);

    int nb_c16 = (N_C + 15) / 16;
    int nb_m16 = (N_M + 15) / 16;

    // ---- Layer 1 (f32 inputs -> fp16 MFMA; aggregate writes fp16 rows) ----
    proj_mfma4_kernel<128, float, 0><<<(N_M + 63) / 64, 256, 0, stream>>>(
        x_m, N_M, wp1A, a1s_mc, a1d_cm, hsA_h, nullptr, nullptr, als_mc, ald_cm);
    proj_mfma4_kernel<128, float, 0><<<(N_C + 63) / 64, 256, 0, stream>>>(
        x_c, N_C, wp1B, a1s_cm, a1d_mc, hsB_h, nullptr, nullptr, als_cm, ald_mc);
    gat_aggregate9<1><<<nb_c16 + nb_m16, 256, 0, stream>>>(
        off_mc, csr_mc, hsA_h, als_mc, ald_mc, b1_mc, zc1_h, N_C,
        off_cm, csr_cm, hsB_h, als_cm, ald_cm, b1_cm, zm1_h, N_M, nb_c16);

    // ---- Layer 2 (fp16 inputs; proj emits per-src q = hs2@Wc_slice, no row tables) ----
    proj_mfma4_kernel<64, __half, 1><<<(N_M + 63) / 64, 256, 0, stream>>>(
        zm1_h, N_M, wp2A, a2s_mc, a2d_cm, nullptr, Wc + 128, qA, als_mc, ald_cm);
    proj_mfma4_kernel<64, __half, 1><<<(N_C + 63) / 64, 256, 0, stream>>>(
        zc1_h, N_C, wp2B, a2s_cm, a2d_mc, nullptr, Wc, qB, als_cm, ald_mc);
    int nb_c256 = (N_C + 255) / 256;
    int nb_m256 = (N_M + 255) / 256;
    // graph0 (mc): dsts = concepts -> pc uses bq_c = bqp[1]; graph1 (cm): materials -> bq_m = bqp[0]
    gat_aggregate10p<<<nb_c256 + nb_m256, 256, 0, stream>>>(
        off_mc, csr_mc, qA, als_mc, ald_mc, bq2, pm_c, N_C,
        off_cm, csr_cm, qB, als_cm, ald_cm, pm_m, N_M, nb_c256);

    // ---- Decoder: out[e] = pm[row] + pc[col] + bc ----
    decoder4_kernel<<<(EL + 255) / 256, 256, 0, stream>>>(rowi, coli, pm_m, pm_c, bc, out, EL);
}